// Round 2
// baseline (948.719 us; speedup 1.0000x reference)
//
#include <hip/hip_runtime.h>
#include <math.h>

#define T_TOK 16384
#define DH 768
#define DF 2048
#define NE 8
#define NSLOT (2 * T_TOK)          // 32768 routed (token,slot) entries
#define MT_R 135                   // max 256-row m-tiles: floor(32768/256)+7
#define NROW_H (MT_R * 256)        // 34560 rows in routed h / y buffers
#define YSPLIT 16384               // y rows [0,16384) alias fc1b (16384*768 bf16)

typedef __attribute__((ext_vector_type(8))) short bf16x8;
typedef __attribute__((ext_vector_type(4))) float f32x4;

__device__ __forceinline__ unsigned short f2bf(float f) {
  union { float f; unsigned int u; } v; v.f = f;
  unsigned int u = v.u;
  u += 0x7fffu + ((u >> 16) & 1u);   // round-to-nearest-even
  return (unsigned short)(u >> 16);
}
__device__ __forceinline__ float bf2f(unsigned short s) {
  union { unsigned int u; float f; } v; v.u = ((unsigned int)s) << 16; return v.f;
}

__device__ __forceinline__ float gelu_exact(float x) {
  return 0.5f * x * (1.0f + erff(x * 0.70710678118654752440f));
}

__device__ __forceinline__ unsigned short* yrow(unsigned short* ylo,
                                                unsigned short* yhi, int s) {
  return (s < YSPLIT) ? (ylo + (long)s * DH) : (yhi + (long)(s - YSPLIT) * DH);
}

// async global->LDS, 16B per lane; lds ptr must be wave-uniform (HW adds lane*16)
__device__ __forceinline__ void async_cp16(void* lds, const void* g) {
  __builtin_amdgcn_global_load_lds(
      (const __attribute__((address_space(1))) unsigned int*)(unsigned long long)g,
      (__attribute__((address_space(3))) unsigned int*)(unsigned int)(unsigned long long)lds,
      16, 0, 0);
}

// ---------------------------------------------------------------------------
__global__ __launch_bounds__(256) void conv_f32_bf16(
    const float* __restrict__ src, unsigned short* __restrict__ dst, int n4) {
  int i = blockIdx.x * blockDim.x + threadIdx.x;
  if (i >= n4) return;
  const float4 v = ((const float4*)src)[i];
  union { unsigned short us[4]; unsigned long long u64; } o;
  o.us[0] = f2bf(v.x); o.us[1] = f2bf(v.y); o.us[2] = f2bf(v.z); o.us[3] = f2bf(v.w);
  ((unsigned long long*)dst)[i] = o.u64;
}

// interleave w1/w3 rows 16-by-16 into Bint[4096][768] bf16:
// h-col c=q*16+t -> w1 row c at Bint[q*32+t], w3 row c at Bint[q*32+16+t]
__global__ __launch_bounds__(192) void conv_interleave_k(
    const float* __restrict__ w1, const float* __restrict__ w3,
    unsigned short* __restrict__ dst) {
  const int row = blockIdx.x;           // 0..4095
  const int q = row >> 5, s = row & 31;
  const float* src = (s < 16) ? &w1[(long)(q * 16 + s) * DH]
                              : &w3[(long)(q * 16 + (s - 16)) * DH];
  const int c = threadIdx.x * 4;
  const float4 v = *(const float4*)&src[c];
  ushort4 o;
  o.x = f2bf(v.x); o.y = f2bf(v.y); o.z = f2bf(v.z); o.w = f2bf(v.w);
  *(ushort4*)&dst[(long)row * DH + c] = o;
}

// ---------------------------------------------------------------------------
// gate phase A: per-token logits (fp32), top-2, renorm weights. NO atomics.
__global__ __launch_bounds__(256) void gate_topk(
    const float* __restrict__ x, const float* __restrict__ gw,
    unsigned short* __restrict__ xb, int* __restrict__ eids,
    float* __restrict__ wts) {
  const int wave = threadIdx.x >> 6;
  const int lane = threadIdx.x & 63;
  const int t = blockIdx.x * 4 + wave;
  float4 xv[3];
#pragma unroll
  for (int i = 0; i < 3; ++i) {
    const int c = i * 256 + lane * 4;
    xv[i] = *(const float4*)&x[(long)t * DH + c];
    ushort4 o;
    o.x = f2bf(xv[i].x); o.y = f2bf(xv[i].y);
    o.z = f2bf(xv[i].z); o.w = f2bf(xv[i].w);
    *(ushort4*)&xb[(long)t * DH + c] = o;
  }
  float s[NE];
#pragma unroll
  for (int e = 0; e < NE; ++e) {
    float a = 0.f;
#pragma unroll
    for (int i = 0; i < 3; ++i) {
      const float4 g = *(const float4*)&gw[e * DH + i * 256 + lane * 4];
      a += xv[i].x * g.x + xv[i].y * g.y + xv[i].z * g.z + xv[i].w * g.w;
    }
    s[e] = a;
  }
#pragma unroll
  for (int off = 32; off >= 1; off >>= 1) {
#pragma unroll
    for (int e = 0; e < NE; ++e) s[e] += __shfl_xor(s[e], off);
  }
  if (lane == 0) {
    float b1 = s[0]; int i1 = 0;
#pragma unroll
    for (int e = 1; e < NE; ++e) { if (s[e] > b1) { b1 = s[e]; i1 = e; } }
    float b2 = -3.4e38f; int i2 = 0;
#pragma unroll
    for (int e = 0; e < NE; ++e) {
      if (e != i1 && s[e] > b2) { b2 = s[e]; i2 = e; }
    }
    const float ex = expf(b2 - b1);
    eids[2 * t]     = i1; wts[2 * t]     = 1.f / (1.f + ex);
    eids[2 * t + 1] = i2; wts[2 * t + 1] = ex / (1.f + ex);
  }
}

// gate phase B: histogram with ballot aggregation; counters padded 256B apart
__global__ __launch_bounds__(256) void hist_k(
    const int* __restrict__ eids, int* __restrict__ hcur) {
  const int j = blockIdx.x * 256 + threadIdx.x;
  const int lane = threadIdx.x & 63;
  const int eid = eids[j];
#pragma unroll
  for (int e = 0; e < NE; ++e) {
    const unsigned long long m = __ballot(eid == e);
    const int tot = __popcll(m);
    if (tot && lane == (__ffsll((long long)m) - 1)) atomicAdd(&hcur[e * 64], tot);
  }
}

// gate phase C: exclusive scan of 256-padded counts (256 = GEMM BM tile)
__global__ void scan_k(const int* __restrict__ hcur, int* __restrict__ sched,
                       int* __restrict__ cur2) {
  if (threadIdx.x == 0) {
    int b = 0;
#pragma unroll
    for (int e = 0; e < NE; ++e) {
      const int c = hcur[e * 64];
      sched[e] = b; sched[9 + e] = c; cur2[e * 64] = b;
      b += (c + 255) & ~255;
    }
    sched[8] = b;
  }
}

// gate phase D: scatter into compacted per-expert slots + inverse map
__global__ __launch_bounds__(256) void scatter_k(
    const int* __restrict__ eids, const float* __restrict__ wts,
    int* __restrict__ cur2, int* __restrict__ slot_tok,
    float* __restrict__ slot_wt, int* __restrict__ slot_pos) {
  const int j = blockIdx.x * 256 + threadIdx.x;
  const int lane = threadIdx.x & 63;
  const int eid = eids[j];
  const float w = wts[j];
#pragma unroll
  for (int e = 0; e < NE; ++e) {
    const unsigned long long m = __ballot(eid == e);
    const int tot = __popcll(m);
    if (!tot) continue;                      // wave-uniform branch
    const int leader = __ffsll((long long)m) - 1;
    int b = 0;
    if (lane == leader) b = atomicAdd(&cur2[e * 64], tot);
    b = __shfl(b, leader);
    if (eid == e) {
      const int pos = b + __popcll(m & ((1ull << lane) - 1));
      slot_tok[pos] = j;                     // token = j>>1
      slot_wt[pos] = w;
      slot_pos[j] = pos;                     // inverse map for combine
    }
  }
}

// ---------------------------------------------------------------------------
// 256x256 bf16 MFMA GEMM, 8-phase counted-vmcnt schedule (T1+T2+T3+T4+T5).
// C = A[MxK] @ W[NxK]^T. 512 threads = 8 waves (2M x 4N), per-wave out 128x64.
// BK=64; LDS = 2 dbuf x (A 32KB + B 32KB) = 128 KB static.
// st_16x32 swizzle: linear LDS dest via global_load_lds with pre-swizzled
// per-lane GLOBAL source col (^16 elems when dest-row bit2 set); ds_read
// applies the same XOR. (rule 21: source-perm == read-perm involution)
// Per K-tile pair (bufs 0,1), 4 phases each, 2 barriers per phase:
//  ph0: ds_read A-lo/B ks0 | stage next-B h0 | BAR | 16 MFMA | BAR
//  ph1: ds_read A-hi ks0 + A-lo/hi/B ks1 | stage next-B h1 | BAR | 16 MFMA
//       | lgkmcnt(0) (this buf now LDS-dead -> restage safe) | BAR
//  ph2: stage next-next-A h0 | BAR | 16 MFMA | BAR
//  ph3: stage next-next-A h1 | vmcnt(4) (certifies next tile) | BAR | 16 MFMA | BAR
// MODE 0: shared fc1, interleaved Bint: h = gelu(a@w1+b1)*(a@w3+b3) -> outH
// MODE 1: routed fc1 (A rows gathered via slot_tok) -> outH (gelu, bf16)
// MODE 2: shared fc2 + combine: out = acc+b + w0*y[s0]+w1*y[s1]
// MODE 3: routed fc2: y[slot] = acc + b (bf16)
// MODE 4: routed fc2 atomic fallback ; MODE 5: shared fc2 plain fallback
#define FENCE asm volatile("" ::: "memory")
#define BAR { FENCE; __builtin_amdgcn_s_barrier(); FENCE; }
#define WAIT_LGKM0 asm volatile("s_waitcnt lgkmcnt(0)" ::: "memory")
#define WAIT_VM4 asm volatile("s_waitcnt vmcnt(4)" ::: "memory")
#define WAIT_VM0 asm volatile("s_waitcnt vmcnt(0)" ::: "memory")

#define RD_A(BUF, MI, KS) \
  (*(const bf16x8*)(aBase + (BUF) * 32768 + (MI) * 2048 + colk[KS] * 2))
#define RD_B(BUF, NI, KS) \
  (*(const bf16x8*)(bBase + (BUF) * 32768 + (NI) * 2048 + colk[KS] * 2))

#define STAGE_A(BUF, H, KO)                                                     \
  {                                                                             \
    async_cp16(smem + (BUF) * 32768 + (H) * 16384 + ldsW, apS##H##0 + (KO));    \
    async_cp16(smem + (BUF) * 32768 + (H) * 16384 + 8192 + ldsW,                \
               apS##H##1 + (KO));                                               \
  }
#define STAGE_B(BUF, H, KO)                                                     \
  {                                                                             \
    async_cp16(smem + 65536 + (BUF) * 32768 + (H) * 16384 + ldsW,               \
               bpS##H##0 + (KO));                                               \
    async_cp16(smem + 65536 + (BUF) * 32768 + (H) * 16384 + 8192 + ldsW,        \
               bpS##H##1 + (KO));                                               \
  }

#define MFMA16(AF, BF, MB)                                                      \
  _Pragma("unroll") for (int mi_ = 0; mi_ < 4; ++mi_) {                         \
    _Pragma("unroll") for (int ni_ = 0; ni_ < 4; ++ni_) {                       \
      acc[(MB) + mi_][ni_] = __builtin_amdgcn_mfma_f32_16x16x32_bf16(           \
          AF[mi_], BF[ni_], acc[(MB) + mi_][ni_], 0, 0, 0);                     \
    }                                                                           \
  }

#define GROUP(BUF, S0, S1, S2, S3, VMW)                                         \
  {                                                                             \
    bf16x8 aA[4], aB[4], aC[4], aD[4], bX[4], bY[4];                            \
    _Pragma("unroll") for (int i = 0; i < 4; ++i) {                             \
      aA[i] = RD_A(BUF, i, 0);                                                  \
      bX[i] = RD_B(BUF, i, 0);                                                  \
    }                                                                           \
    S0;                                                                         \
    BAR;                                                                        \
    __builtin_amdgcn_s_setprio(1);                                              \
    MFMA16(aA, bX, 0);                                                          \
    __builtin_amdgcn_s_setprio(0);                                              \
    BAR;                                                                        \
    _Pragma("unroll") for (int i = 0; i < 4; ++i) {                             \
      aB[i] = RD_A(BUF, 4 + i, 0);                                              \
      aC[i] = RD_A(BUF, i, 1);                                                  \
      aD[i] = RD_A(BUF, 4 + i, 1);                                              \
      bY[i] = RD_B(BUF, i, 1);                                                  \
    }                                                                           \
    S1;                                                                         \
    BAR;                                                                        \
    __builtin_amdgcn_s_setprio(1);                                              \
    MFMA16(aB, bX, 4);                                                          \
    __builtin_amdgcn_s_setprio(0);                                              \
    WAIT_LGKM0;                                                                 \
    BAR;                                                                        \
    S2;                                                                         \
    BAR;                                                                        \
    __builtin_amdgcn_s_setprio(1);                                              \
    MFMA16(aC, bY, 0);                                                          \
    __builtin_amdgcn_s_setprio(0);                                              \
    BAR;                                                                        \
    S3;                                                                         \
    VMW;                                                                        \
    BAR;                                                                        \
    __builtin_amdgcn_s_setprio(1);                                              \
    MFMA16(aD, bY, 4);                                                          \
    __builtin_amdgcn_s_setprio(0);                                              \
    BAR;                                                                        \
  }

template <int MODE, int KDIM, int GX, int GTOT>
__global__ __launch_bounds__(512, 2) void gemm8_k(
    const unsigned short* __restrict__ A, const unsigned short* __restrict__ B1,
    const float* __restrict__ bias1, const float* __restrict__ bias2,
    float* __restrict__ outF, unsigned short* __restrict__ outH,
    const int* __restrict__ sched, const int* __restrict__ slot_tok,
    const int* __restrict__ slot_pos, const float* __restrict__ wts,
    unsigned short* __restrict__ ylo, unsigned short* __restrict__ yhi) {
  constexpr int NT = KDIM / 64;      // K-tiles (768->12, 2048->32), even
  constexpr int NT2 = NT / 2;
  constexpr int Q = GTOT / 8, R = GTOT % 8;
  static __shared__ __align__(16) char smem[131072];

  // bijective XCD swizzle (m204): n-tile fastest within an XCD chunk
  const int id = blockIdx.x;
  const int xcd = id & 7, pos = id >> 3;
  const int wg = (xcd < R ? xcd * (Q + 1) : R * (Q + 1) + (xcd - R) * Q) + pos;
  const int n0 = (wg % GX) * 256;
  const int m0 = (wg / GX) * 256;

  const int tid = threadIdx.x;
  const int w8 = tid >> 6;
  const int lane = tid & 63;
  const int wm = w8 >> 2, wn = w8 & 3;     // wave grid 2(M) x 4(N)
  const int l16 = lane & 15, quad = lane >> 4;

  const unsigned short* Bbase = B1;
  const float* bias = bias1;
  int cnt_end = 0;
  if constexpr (MODE == 1 || MODE == 3 || MODE == 4) {
    if (m0 >= sched[8]) return;            // block-uniform exit, before barriers
    int e = 0;
#pragma unroll
    for (int i = 1; i < NE; ++i) { if (m0 >= sched[i]) e = i; }
    cnt_end = sched[e] + sched[9 + e];     // base[e] + count[e]
    Bbase = B1 + (long)e * ((long)DF * DH);
    bias = bias1 + e * ((MODE == 1) ? DF : DH);
  }

  // staging source pointers (pre-swizzled global col: ^16 elems when row bit2 set)
  const int scol = ((lane & 7) << 3) ^ ((lane & 32) >> 1);
  auto asrc = [&](int hh, int j) -> const unsigned short* {
    const int rr = j * 64 + w8 * 8 + (lane >> 3);
    long arow;
    if constexpr (MODE == 1) {
      const int slot = m0 + hh * 128 + rr;
      arow = (slot < cnt_end) ? (long)(slot_tok[slot] >> 1) : 0L;
    } else {
      arow = (long)(m0 + hh * 128 + rr);
    }
    return A + arow * KDIM + scol;
  };
  auto bsrc = [&](int hh, int j) -> const unsigned short* {
    const int rr = j * 64 + w8 * 8 + (lane >> 3);
    return Bbase + (long)(n0 + hh * 128 + rr) * KDIM + scol;
  };
  const unsigned short* apS00 = asrc(0, 0);
  const unsigned short* apS01 = asrc(0, 1);
  const unsigned short* apS10 = asrc(1, 0);
  const unsigned short* apS11 = asrc(1, 1);
  const unsigned short* bpS00 = bsrc(0, 0);
  const unsigned short* bpS01 = bsrc(0, 1);
  const unsigned short* bpS10 = bsrc(1, 0);
  const unsigned short* bpS11 = bsrc(1, 1);
  const int ldsW = w8 * 1024;

  // ds_read fragment bases; read-side XOR matches staged layout
  const int swz = ((l16 >> 2) & 1) << 4;
  const int colk[2] = { (quad * 8) ^ swz, (32 + quad * 8) ^ swz };
  const char* aBase = smem + (wm * 128 + l16) * 128;
  const char* bBase = smem + 65536 + (wn * 64 + l16) * 128;

  f32x4 acc[8][4];
#pragma unroll
  for (int i = 0; i < 8; ++i)
#pragma unroll
    for (int j = 0; j < 4; ++j) acc[i][j] = {0.f, 0.f, 0.f, 0.f};

  // prologue: tile0 complete + tile1 A halves; vmcnt(4) certifies tile0
  STAGE_A(0, 0, 0) STAGE_A(0, 1, 0) STAGE_B(0, 0, 0) STAGE_B(0, 1, 0)
  STAGE_A(1, 0, 64) STAGE_A(1, 1, 64)
  WAIT_VM4;
  BAR;

  int ko = 0;
#pragma unroll 1
  for (int it = 0; it < NT2 - 1; ++it, ko += 128) {
    GROUP(0, STAGE_B(1, 0, ko + 64), STAGE_B(1, 1, ko + 64),
          STAGE_A(0, 0, ko + 128), STAGE_A(0, 1, ko + 128), WAIT_VM4)
    GROUP(1, STAGE_B(0, 0, ko + 128), STAGE_B(0, 1, ko + 128),
          STAGE_A(1, 0, ko + 192), STAGE_A(1, 1, ko + 192), WAIT_VM4)
  }
  // final pair: only B(NT-1) left to stage; drain fully before last tile
  GROUP(0, STAGE_B(1, 0, ko + 64), STAGE_B(1, 1, ko + 64), (void)0, (void)0,
        WAIT_VM0)
  GROUP(1, (void)0, (void)0, (void)0, (void)0, (void)0)

  // epilogue; C/D layout: row = quad*4 + reg, col = lane&15 (m89-verified)
  const int ccol0 = n0 + wn * 64;
#pragma unroll
  for (int mi = 0; mi < 8; ++mi) {
#pragma unroll
    for (int r = 0; r < 4; ++r) {
      const int row = m0 + wm * 128 + mi * 16 + quad * 4 + r;
      if constexpr (MODE == 1) {
#pragma unroll
        for (int ni = 0; ni < 4; ++ni) {
          const int c = ccol0 + ni * 16 + l16;
          outH[(long)row * DF + c] = f2bf(gelu_exact(acc[mi][ni][r] + bias[c]));
        }
      } else if constexpr (MODE == 0) {
        // Bint rows interleave w1/w3 16-by-16: ni even = w1, ni odd = w3 of
        // the same 16 h-cols. h-col = (n0>>1) + wn*32 + p*16 + l16.
#pragma unroll
        for (int p = 0; p < 2; ++p) {
          const int ch = (n0 >> 1) + wn * 32 + p * 16 + l16;
          const float h1 = acc[mi][2 * p][r] + bias1[ch];
          const float h3 = acc[mi][2 * p + 1][r] + bias2[ch];
          outH[(long)row * DF + ch] = f2bf(gelu_exact(h1) * h3);
        }
      } else if constexpr (MODE == 3) {
        unsigned short* yr = yrow(ylo, yhi, row);
#pragma unroll
        for (int ni = 0; ni < 4; ++ni) {
          const int c = ccol0 + ni * 16 + l16;
          yr[c] = f2bf(acc[mi][ni][r] + bias[c]);
        }
      } else if constexpr (MODE == 2) {
        const int s0 = slot_pos[2 * row], s1 = slot_pos[2 * row + 1];
        const float w0v = wts[2 * row], w1v = wts[2 * row + 1];
        const unsigned short* y0 = yrow(ylo, yhi, s0);
        const unsigned short* y1 = yrow(ylo, yhi, s1);
#pragma unroll
        for (int ni = 0; ni < 4; ++ni) {
          const int c = ccol0 + ni * 16 + l16;
          outF[(long)row * DH + c] =
              acc[mi][ni][r] + bias1[c] + w0v * bf2f(y0[c]) + w1v * bf2f(y1[c]);
        }
      } else if constexpr (MODE == 5) {
#pragma unroll
        for (int ni = 0; ni < 4; ++ni) {
          const int c = ccol0 + ni * 16 + l16;
          outF[(long)row * DH + c] = acc[mi][ni][r] + bias1[c];
        }
      } else {  // MODE 4: routed fc2 atomic fallback
        if (row < cnt_end) {
          const int t = slot_tok[row] >> 1;
          const float w = wts[row];            // slot_wt passed in wts param
#pragma unroll
          for (int ni = 0; ni < 4; ++ni) {
            const int c = ccol0 + ni * 16 + l16;
            atomicAdd(&outF[(long)t * DH + c], w * (acc[mi][ni][r] + bias[c]));
          }
        }
      }
    }
  }
}

// ---------------------------------------------------------------------------
extern "C" void kernel_launch(void* const* d_in, const int* in_sizes, int n_in,
                              void* d_out, int out_size, void* d_ws, size_t ws_size,
                              hipStream_t stream) {
  const float* x     = (const float*)d_in[0];
  const float* gw    = (const float*)d_in[1];
  const float* fc1w  = (const float*)d_in[2];
  const float* fc1bs = (const float*)d_in[3];
  const float* fc2w  = (const float*)d_in[4];
  const float* fc2bs = (const float*)d_in[5];
  const float* w1w   = (const float*)d_in[6];
  const float* w1bs  = (const float*)d_in[7];
  const float* w3w   = (const float*)d_in[8];
  const float* w3bs  = (const float*)d_in[9];
  const float* w2w   = (const float*)d_in[10];
  const float* w2bs  = (const float*)d_in[11];
  float* out = (float*)d_out;

  char* p = (char*)d_ws;
  auto take = [&](size_t b) { char* r = p; p += (b + 255) & ~(size_t)255; return r; };
  unsigned short* xb   = (unsigned short*)take((size_t)T_TOK * DH * 2);
  unsigned short* fc1b = (unsigned short*)take((size_t)NE * DF * DH * 2);
  unsigned short* fc2b = (unsigned short*)take((size_t)NE * DH * DF * 2);
  unsigned short* bint = (unsigned short*)take((size_t)2 * DF * DH * 2);  // w1/w3 zip
  unsigned short* w2b  = (unsigned short*)take((size_t)DH * DF * 2);
  unsigned short* h    = (unsigned short*)take((size_t)NROW_H * DF * 2);
  int*   eids     = (int*)take((size_t)NSLOT * 4);
  float* wts      = (float*)take((size_t)NSLOT * 4);
  int*   hcur     = (int*)take(NE * 64 * 4);
  int*   cur2     = (int*)take(NE * 64 * 4);
  int*   sched    = (int*)take(32 * 4);
  int*   slot_tok = (int*)take((size_t)NROW_H * 4);
  float* slot_wt  = (float*)take((size_t)NROW_H * 4);
  int*   slot_pos = (int*)take((size_t)NSLOT * 4);

  // path A extra: y rows [0,16384) alias fc1b (exactly 16384*768 bf16, dead
  // after routed fc1); rows [16384, NROW_H) get a dedicated region.
  const size_t yhi_bytes = (size_t)(NROW_H - YSPLIT) * DH * 2;
  const bool pathA = ((size_t)(p - (char*)d_ws) + yhi_bytes) <= ws_size;
  unsigned short* ylo = fc1b;
  unsigned short* yhi = pathA ? (unsigned short*)take(yhi_bytes) : nullptr;

  hipMemsetAsync(hcur, 0, NE * 64 * sizeof(int), stream);

  auto conv = [&](const float* s, unsigned short* d, long n) {
    int n4 = (int)(n >> 2);
    conv_f32_bf16<<<(n4 + 255) / 256, 256, 0, stream>>>(s, d, n4);
  };
  conv(fc1w, fc1b, (long)NE * DF * DH);
  conv(fc2w, fc2b, (long)NE * DH * DF);
  conv(w2w, w2b, (long)DH * DF);
  conv_interleave_k<<<2 * DF, 192, 0, stream>>>(w1w, w3w, bint);

  // gate: topk (no atomics) -> histogram -> scan -> scatter
  gate_topk<<<T_TOK / 4, 256, 0, stream>>>(x, gw, xb, eids, wts);
  hist_k<<<NSLOT / 256, 256, 0, stream>>>(eids, hcur);
  scan_k<<<1, 64, 0, stream>>>(hcur, sched, cur2);
  scatter_k<<<NSLOT / 256, 256, 0, stream>>>(eids, wts, cur2, slot_tok, slot_wt,
                                             slot_pos);

  if (pathA) {
    // routed fc1 -> routed fc2 (y rows) -> shared fc1 -> shared fc2+combine
    gemm8_k<1, DH, 8, 8 * MT_R><<<8 * MT_R, 512, 0, stream>>>(
        xb, fc1b, fc1bs, nullptr, nullptr, h,
        sched, slot_tok, nullptr, nullptr, nullptr, nullptr);
    gemm8_k<3, DF, 3, 3 * MT_R><<<3 * MT_R, 512, 0, stream>>>(
        h, fc2b, fc2bs, nullptr, nullptr, nullptr,
        sched, nullptr, nullptr, nullptr, ylo, yhi);
    gemm8_k<0, DH, 16, 1024><<<1024, 512, 0, stream>>>(
        xb, bint, w1bs, w3bs, nullptr, h,
        nullptr, nullptr, nullptr, nullptr, nullptr, nullptr);
    gemm8_k<2, DF, 3, 192><<<192, 512, 0, stream>>>(
        h, w2b, w2bs, nullptr, out, nullptr,
        nullptr, nullptr, slot_pos, wts, ylo, yhi);
  } else {
    // fallback: shared plain, routed atomic (no y aliasing needed)
    gemm8_k<0, DH, 16, 1024><<<1024, 512, 0, stream>>>(
        xb, bint, w1bs, w3bs, nullptr, h,
        nullptr, nullptr, nullptr, nullptr, nullptr, nullptr);
    gemm8_k<5, DF, 3, 192><<<192, 512, 0, stream>>>(
        h, w2b, w2bs, nullptr, out, nullptr,
        nullptr, nullptr, nullptr, nullptr, nullptr, nullptr);
    gemm8_k<1, DH, 8, 8 * MT_R><<<8 * MT_R, 512, 0, stream>>>(
        xb, fc1b, fc1bs, nullptr, nullptr, h,
        sched, slot_tok, nullptr, nullptr, nullptr, nullptr);
    gemm8_k<4, DF, 3, 3 * MT_R><<<3 * MT_R, 512, 0, stream>>>(
        h, fc2b, fc2bs, nullptr, out, nullptr,
        sched, slot_tok, nullptr, slot_wt, nullptr, nullptr);
  }
}

// Round 3
// 889.957 us; speedup vs baseline: 1.0660x; 1.0660x over previous
//
#include <hip/hip_runtime.h>
#include <math.h>

#define T_TOK 16384
#define DH 768
#define DF 2048
#define NE 8
#define NSLOT (2 * T_TOK)          // 32768 routed (token,slot) entries
#define MT_R 135                   // max 256-row m-tiles: 128 + 7 worst-case pad
#define NROW_H (MT_R * 256)        // 34560 rows in routed h / y buffers
#define YSPLIT 16384               // y rows [0,16384) alias fc1b (16384*768 bf16)

typedef __attribute__((ext_vector_type(8))) short bf16x8;
typedef __attribute__((ext_vector_type(4))) float f32x4;

__device__ __forceinline__ unsigned short f2bf(float f) {
  union { float f; unsigned int u; } v; v.f = f;
  unsigned int u = v.u;
  u += 0x7fffu + ((u >> 16) & 1u);   // round-to-nearest-even
  return (unsigned short)(u >> 16);
}
__device__ __forceinline__ float bf2f(unsigned short s) {
  union { unsigned int u; float f; } v; v.u = ((unsigned int)s) << 16; return v.f;
}

__device__ __forceinline__ float gelu_exact(float x) {
  return 0.5f * x * (1.0f + erff(x * 0.70710678118654752440f));
}

__device__ __forceinline__ unsigned short* yrow(unsigned short* ylo,
                                                unsigned short* yhi, int s) {
  return (s < YSPLIT) ? (ylo + (long)s * DH) : (yhi + (long)(s - YSPLIT) * DH);
}

// async global->LDS, 16B per lane; lds ptr must be wave-uniform (HW adds lane*16)
__device__ __forceinline__ void async_cp16(void* lds, const void* g) {
  __builtin_amdgcn_global_load_lds(
      (const __attribute__((address_space(1))) unsigned int*)(unsigned long long)g,
      (__attribute__((address_space(3))) unsigned int*)(unsigned int)(unsigned long long)lds,
      16, 0, 0);
}

// ---------------------------------------------------------------------------
__global__ __launch_bounds__(256) void conv_f32_bf16(
    const float* __restrict__ src, unsigned short* __restrict__ dst, int n4) {
  int i = blockIdx.x * blockDim.x + threadIdx.x;
  if (i >= n4) return;
  const float4 v = ((const float4*)src)[i];
  union { unsigned short us[4]; unsigned long long u64; } o;
  o.us[0] = f2bf(v.x); o.us[1] = f2bf(v.y); o.us[2] = f2bf(v.z); o.us[3] = f2bf(v.w);
  ((unsigned long long*)dst)[i] = o.u64;
}

// interleave w1/w3 rows 16-by-16 into Bint[4096][768] bf16:
// h-col c=q*16+t -> w1 row c at Bint[q*32+t], w3 row c at Bint[q*32+16+t]
__global__ __launch_bounds__(192) void conv_interleave_k(
    const float* __restrict__ w1, const float* __restrict__ w3,
    unsigned short* __restrict__ dst) {
  const int row = blockIdx.x;           // 0..4095
  const int q = row >> 5, s = row & 31;
  const float* src = (s < 16) ? &w1[(long)(q * 16 + s) * DH]
                              : &w3[(long)(q * 16 + (s - 16)) * DH];
  const int c = threadIdx.x * 4;
  const float4 v = *(const float4*)&src[c];
  ushort4 o;
  o.x = f2bf(v.x); o.y = f2bf(v.y); o.z = f2bf(v.z); o.w = f2bf(v.w);
  *(ushort4*)&dst[(long)row * DH + c] = o;
}

// ---------------------------------------------------------------------------
// gate phase A: per-token logits (fp32), top-2, renorm weights. NO atomics.
__global__ __launch_bounds__(256) void gate_topk(
    const float* __restrict__ x, const float* __restrict__ gw,
    unsigned short* __restrict__ xb, int* __restrict__ eids,
    float* __restrict__ wts) {
  const int wave = threadIdx.x >> 6;
  const int lane = threadIdx.x & 63;
  const int t = blockIdx.x * 4 + wave;
  float4 xv[3];
#pragma unroll
  for (int i = 0; i < 3; ++i) {
    const int c = i * 256 + lane * 4;
    xv[i] = *(const float4*)&x[(long)t * DH + c];
    ushort4 o;
    o.x = f2bf(xv[i].x); o.y = f2bf(xv[i].y);
    o.z = f2bf(xv[i].z); o.w = f2bf(xv[i].w);
    *(ushort4*)&xb[(long)t * DH + c] = o;
  }
  float s[NE];
#pragma unroll
  for (int e = 0; e < NE; ++e) {
    float a = 0.f;
#pragma unroll
    for (int i = 0; i < 3; ++i) {
      const float4 g = *(const float4*)&gw[e * DH + i * 256 + lane * 4];
      a += xv[i].x * g.x + xv[i].y * g.y + xv[i].z * g.z + xv[i].w * g.w;
    }
    s[e] = a;
  }
#pragma unroll
  for (int off = 32; off >= 1; off >>= 1) {
#pragma unroll
    for (int e = 0; e < NE; ++e) s[e] += __shfl_xor(s[e], off);
  }
  if (lane == 0) {
    float b1 = s[0]; int i1 = 0;
#pragma unroll
    for (int e = 1; e < NE; ++e) { if (s[e] > b1) { b1 = s[e]; i1 = e; } }
    float b2 = -3.4e38f; int i2 = 0;
#pragma unroll
    for (int e = 0; e < NE; ++e) {
      if (e != i1 && s[e] > b2) { b2 = s[e]; i2 = e; }
    }
    const float ex = expf(b2 - b1);
    eids[2 * t]     = i1; wts[2 * t]     = 1.f / (1.f + ex);
    eids[2 * t + 1] = i2; wts[2 * t + 1] = ex / (1.f + ex);
  }
}

// gate phase B: histogram with ballot aggregation; counters padded 256B apart
__global__ __launch_bounds__(256) void hist_k(
    const int* __restrict__ eids, int* __restrict__ hcur) {
  const int j = blockIdx.x * 256 + threadIdx.x;
  const int lane = threadIdx.x & 63;
  const int eid = eids[j];
#pragma unroll
  for (int e = 0; e < NE; ++e) {
    const unsigned long long m = __ballot(eid == e);
    const int tot = __popcll(m);
    if (tot && lane == (__ffsll((long long)m) - 1)) atomicAdd(&hcur[e * 64], tot);
  }
}

// gate phase C: exclusive scan of 256-padded counts (256 = GEMM BM tile)
__global__ void scan_k(const int* __restrict__ hcur, int* __restrict__ sched,
                       int* __restrict__ cur2) {
  if (threadIdx.x == 0) {
    int b = 0;
#pragma unroll
    for (int e = 0; e < NE; ++e) {
      const int c = hcur[e * 64];
      sched[e] = b; sched[9 + e] = c; cur2[e * 64] = b;
      b += (c + 255) & ~255;
    }
    sched[8] = b;
  }
}

// gate phase D: scatter into compacted per-expert slots + inverse map
__global__ __launch_bounds__(256) void scatter_k(
    const int* __restrict__ eids, const float* __restrict__ wts,
    int* __restrict__ cur2, int* __restrict__ slot_tok,
    float* __restrict__ slot_wt, int* __restrict__ slot_pos) {
  const int j = blockIdx.x * 256 + threadIdx.x;
  const int lane = threadIdx.x & 63;
  const int eid = eids[j];
  const float w = wts[j];
#pragma unroll
  for (int e = 0; e < NE; ++e) {
    const unsigned long long m = __ballot(eid == e);
    const int tot = __popcll(m);
    if (!tot) continue;                      // wave-uniform branch
    const int leader = __ffsll((long long)m) - 1;
    int b = 0;
    if (lane == leader) b = atomicAdd(&cur2[e * 64], tot);
    b = __shfl(b, leader);
    if (eid == e) {
      const int pos = b + __popcll(m & ((1ull << lane) - 1));
      slot_tok[pos] = j;                     // token = j>>1
      slot_wt[pos] = w;
      slot_pos[j] = pos;                     // inverse map for combine
    }
  }
}

// ---------------------------------------------------------------------------
// 256x256 bf16 MFMA GEMM, 8-phase counted-vmcnt schedule (T1..T5).
// C = A[MxK] @ W[NxK]^T. 512 threads = 8 waves (2M x 4N), per-wave out 128x64.
// BK=64, split into ks-half REGIONS of 256 rows x 32 k (16 KB = 2 load insts).
// LDS 128 KB: A[P][ks] at P*32768+ks*16384; B[P][ks] at +65536.
// Region layout: elem = row*32 + 8*(chunk ^ ((row>>1)&3)); chunk = gcol/8.
//   -> staging (linear LDS dest) uses pre-permuted GLOBAL col
//      scol = 8*((lane&3)^((lane>>3)&3)), row = ih*128 + w8*16 + lane/4.
//   -> ds_read_b128 slot bits[6:4] = (row&1)<<2 | (quad^((row>>1)&3)):
//      16 lanes -> 8 slots x 2 = 2-way conflict = free (m136).
// Per K-tile group (4 phases, each: {own ds_reads | 1 region stage (2 loads) |
// BAR | setprio1 MFMA16 setprio0 | [vmcnt(8)] | BAR}):
//  ph0: A-lo+B ks0, stage A(j+1)ks1 ; ph1: A-hi ks0, stage B(j+1)ks1, VM8
//  ph2: A-lo+B ks1, stage A(j+2)ks0 ; ph3: A-hi ks1, stage B(j+2)ks0, VM8
// Ledger: 8 loads outstanding after each checkpoint; each vmcnt(8) certifies
// exactly the region read 2 phases later. Tail: VM4 then VM0 (peeled groups).
// MODE 0: shared fc1, interleaved Bint: h = gelu(a@w1+b1)*(a@w3+b3) -> outH
// MODE 1: routed fc1 (A rows gathered via slot_tok) -> outH (gelu, bf16)
// MODE 2: shared fc2 + combine: out = acc+b + w0*y[s0]+w1*y[s1]
// MODE 3: routed fc2: y[slot] = acc + b (bf16)
// MODE 4: routed fc2 atomic fallback ; MODE 5: shared fc2 plain fallback
#define FENCE asm volatile("" ::: "memory")
#define BAR { FENCE; __builtin_amdgcn_s_barrier(); FENCE; }
#define WAIT_VM8 asm volatile("s_waitcnt vmcnt(8)" ::: "memory")
#define WAIT_VM4 asm volatile("s_waitcnt vmcnt(4)" ::: "memory")
#define WAIT_VM0 asm volatile("s_waitcnt vmcnt(0)" ::: "memory")

#define RD_A(P, MI, KS) \
  (*(const bf16x8*)(smem + (P) * 32768 + (KS) * 16384 + (MI) * 1024 + aoff))
#define RD_B(P, NI, KS) \
  (*(const bf16x8*)(smem + 65536 + (P) * 32768 + (KS) * 16384 + (NI) * 1024 + boff))

#define STAGE_A(P, KS, GOFF)                                                    \
  {                                                                             \
    async_cp16(smem + (P) * 32768 + (KS) * 16384 + ldsW, apS0 + (GOFF));        \
    async_cp16(smem + (P) * 32768 + (KS) * 16384 + 8192 + ldsW, apS1 + (GOFF)); \
  }
#define STAGE_B(P, KS, GOFF)                                                    \
  {                                                                             \
    async_cp16(smem + 65536 + (P) * 32768 + (KS) * 16384 + ldsW,                \
               bpS0 + (GOFF));                                                  \
    async_cp16(smem + 65536 + (P) * 32768 + (KS) * 16384 + 8192 + ldsW,         \
               bpS1 + (GOFF));                                                  \
  }

#define MFMA16(AF, BF, MB)                                                      \
  _Pragma("unroll") for (int mi_ = 0; mi_ < 4; ++mi_) {                         \
    _Pragma("unroll") for (int ni_ = 0; ni_ < 4; ++ni_) {                       \
      acc[(MB) + mi_][ni_] = __builtin_amdgcn_mfma_f32_16x16x32_bf16(           \
          AF[mi_], BF[ni_], acc[(MB) + mi_][ni_], 0, 0, 0);                     \
    }                                                                           \
  }

#define GROUP(P, S0, S1, S2, S3, VW1, VW2)                                      \
  {                                                                             \
    bf16x8 fA[4], fB[4];                                                        \
    _Pragma("unroll") for (int i = 0; i < 4; ++i) {                             \
      fA[i] = RD_A(P, i, 0); fB[i] = RD_B(P, i, 0);                             \
    }                                                                           \
    S0; BAR;                                                                    \
    __builtin_amdgcn_s_setprio(1); MFMA16(fA, fB, 0);                           \
    __builtin_amdgcn_s_setprio(0); BAR;                                         \
    _Pragma("unroll") for (int i = 0; i < 4; ++i) fA[i] = RD_A(P, 4 + i, 0);    \
    S1; BAR;                                                                    \
    __builtin_amdgcn_s_setprio(1); MFMA16(fA, fB, 4);                           \
    __builtin_amdgcn_s_setprio(0); VW1; BAR;                                    \
    _Pragma("unroll") for (int i = 0; i < 4; ++i) {                             \
      fA[i] = RD_A(P, i, 1); fB[i] = RD_B(P, i, 1);                             \
    }                                                                           \
    S2; BAR;                                                                    \
    __builtin_amdgcn_s_setprio(1); MFMA16(fA, fB, 0);                           \
    __builtin_amdgcn_s_setprio(0); BAR;                                         \
    _Pragma("unroll") for (int i = 0; i < 4; ++i) fA[i] = RD_A(P, 4 + i, 1);    \
    S3; BAR;                                                                    \
    __builtin_amdgcn_s_setprio(1); MFMA16(fA, fB, 4);                           \
    __builtin_amdgcn_s_setprio(0); VW2; BAR;                                    \
  }

template <int MODE, int KDIM, int GX, int GTOT>
__global__ __launch_bounds__(512, 2) void gemm8_k(
    const unsigned short* __restrict__ A, const unsigned short* __restrict__ B1,
    const float* __restrict__ bias1, const float* __restrict__ bias2,
    float* __restrict__ outF, unsigned short* __restrict__ outH,
    const int* __restrict__ sched, const int* __restrict__ slot_tok,
    const int* __restrict__ slot_pos, const float* __restrict__ wts,
    unsigned short* __restrict__ ylo, unsigned short* __restrict__ yhi) {
  constexpr int NT = KDIM / 64;      // K-tiles (768->12, 2048->32), even, >=4
  constexpr int NT2 = NT / 2;
  constexpr int Q = GTOT / 8, R = GTOT % 8;
  static __shared__ __align__(16) char smem[131072];

  // bijective XCD swizzle (m204): n-tile fastest within an XCD chunk
  const int id = blockIdx.x;
  const int xcd = id & 7, pos = id >> 3;
  const int wg = (xcd < R ? xcd * (Q + 1) : R * (Q + 1) + (xcd - R) * Q) + pos;
  const int n0 = (wg % GX) * 256;
  const int m0 = (wg / GX) * 256;

  const int tid = threadIdx.x;
  const int w8 = tid >> 6;
  const int lane = tid & 63;
  const int wm = w8 >> 2, wn = w8 & 3;     // wave grid 2(M) x 4(N)
  const int l16 = lane & 15, quad = lane >> 4;

  const unsigned short* Bbase = B1;
  const float* bias = bias1;
  int cnt_end = 0;
  if constexpr (MODE == 1 || MODE == 3 || MODE == 4) {
    if (m0 >= sched[8]) return;            // block-uniform exit, before barriers
    int e = 0;
#pragma unroll
    for (int i = 1; i < NE; ++i) { if (m0 >= sched[i]) e = i; }
    cnt_end = sched[e] + sched[9 + e];     // base[e] + count[e]
    Bbase = B1 + (long)e * ((long)DF * DH);
    bias = bias1 + e * ((MODE == 1) ? DF : DH);
  }

  // staging source pointers; pre-permuted global chunk = (lane&3)^((lane>>3)&3)
  const int rr = w8 * 16 + (lane >> 2);    // row within 128-row inst-half
  const int scol = (((lane & 3) ^ ((lane >> 3) & 3)) << 3);
  long ar0, ar1;
  if constexpr (MODE == 1) {
    const int s0i = m0 + rr, s1i = m0 + 128 + rr;
    ar0 = (s0i < cnt_end) ? (long)(slot_tok[s0i] >> 1) : 0L;
    ar1 = (s1i < cnt_end) ? (long)(slot_tok[s1i] >> 1) : 0L;
  } else {
    ar0 = (long)(m0 + rr);
    ar1 = (long)(m0 + 128 + rr);
  }
  const unsigned short* apS0 = A + ar0 * KDIM + scol;
  const unsigned short* apS1 = A + ar1 * KDIM + scol;
  const unsigned short* bpS0 = Bbase + (long)(n0 + rr) * KDIM + scol;
  const unsigned short* bpS1 = Bbase + (long)(n0 + 128 + rr) * KDIM + scol;
  const int ldsW = w8 * 1024;

  // ds_read offsets (bytes): row*64 + 16*(quad ^ ((row>>1)&3)), row%16 = l16
  const int rsw = ((quad ^ ((l16 >> 1) & 3)) << 4);
  const int aoff = (wm * 128 + l16) * 64 + rsw;
  const int boff = (wn * 64 + l16) * 64 + rsw;

  f32x4 acc[8][4];
#pragma unroll
  for (int i = 0; i < 8; ++i)
#pragma unroll
    for (int j = 0; j < 4; ++j) acc[i][j] = {0.f, 0.f, 0.f, 0.f};

  // prologue: tile0 (both ks) + tile1 ks0; vmcnt(8) certifies tile0 ks0
  STAGE_A(0, 0, 0) STAGE_B(0, 0, 0)
  STAGE_A(0, 1, 32) STAGE_B(0, 1, 32)
  STAGE_A(1, 0, 64) STAGE_B(1, 0, 64)
  WAIT_VM8;
  BAR;

  int ko = 0;
#pragma unroll 1
  for (int it = 0; it < NT2 - 1; ++it, ko += 128) {
    // tile j=2it (buf0): stage A/B(j+1)ks1 -> buf1; A/B(j+2)ks0 -> buf0
    GROUP(0, STAGE_A(1, 1, ko + 96),  STAGE_B(1, 1, ko + 96),
             STAGE_A(0, 0, ko + 128), STAGE_B(0, 0, ko + 128),
          WAIT_VM8, WAIT_VM8)
    // tile j+1 (buf1): stage A/B(j+2)ks1 -> buf0; A/B(j+3)ks0 -> buf1
    GROUP(1, STAGE_A(0, 1, ko + 160), STAGE_B(0, 1, ko + 160),
             STAGE_A(1, 0, ko + 192), STAGE_B(1, 0, ko + 192),
          WAIT_VM8, WAIT_VM8)
  }
  // tile NT-2 (buf0): only (NT-1)ks1 left to stage; certify (NT-1)ks0 at end
  GROUP(0, STAGE_A(1, 1, ko + 96), STAGE_B(1, 1, ko + 96), (void)0, (void)0,
        WAIT_VM8, WAIT_VM4)
  // tile NT-1 (buf1): nothing to stage; certify its ks1 before ph2
  GROUP(1, (void)0, (void)0, (void)0, (void)0, WAIT_VM0, (void)0)

  // epilogue; C/D layout: row = quad*4 + reg, col = lane&15 (m89-verified)
  const int ccol0 = n0 + wn * 64;
#pragma unroll
  for (int mi = 0; mi < 8; ++mi) {
#pragma unroll
    for (int r = 0; r < 4; ++r) {
      const int row = m0 + wm * 128 + mi * 16 + quad * 4 + r;
      if constexpr (MODE == 1) {
#pragma unroll
        for (int ni = 0; ni < 4; ++ni) {
          const int c = ccol0 + ni * 16 + l16;
          outH[(long)row * DF + c] = f2bf(gelu_exact(acc[mi][ni][r] + bias[c]));
        }
      } else if constexpr (MODE == 0) {
        // Bint rows interleave w1/w3 16-by-16: ni even = w1, ni odd = w3 of
        // the same 16 h-cols. h-col = (n0>>1) + wn*32 + p*16 + l16.
#pragma unroll
        for (int p = 0; p < 2; ++p) {
          const int ch = (n0 >> 1) + wn * 32 + p * 16 + l16;
          const float h1 = acc[mi][2 * p][r] + bias1[ch];
          const float h3 = acc[mi][2 * p + 1][r] + bias2[ch];
          outH[(long)row * DF + ch] = f2bf(gelu_exact(h1) * h3);
        }
      } else if constexpr (MODE == 3) {
        unsigned short* yr = yrow(ylo, yhi, row);
#pragma unroll
        for (int ni = 0; ni < 4; ++ni) {
          const int c = ccol0 + ni * 16 + l16;
          yr[c] = f2bf(acc[mi][ni][r] + bias[c]);
        }
      } else if constexpr (MODE == 2) {
        const int s0 = slot_pos[2 * row], s1 = slot_pos[2 * row + 1];
        const float w0v = wts[2 * row], w1v = wts[2 * row + 1];
        const unsigned short* y0 = yrow(ylo, yhi, s0);
        const unsigned short* y1 = yrow(ylo, yhi, s1);
#pragma unroll
        for (int ni = 0; ni < 4; ++ni) {
          const int c = ccol0 + ni * 16 + l16;
          outF[(long)row * DH + c] =
              acc[mi][ni][r] + bias1[c] + w0v * bf2f(y0[c]) + w1v * bf2f(y1[c]);
        }
      } else if constexpr (MODE == 5) {
#pragma unroll
        for (int ni = 0; ni < 4; ++ni) {
          const int c = ccol0 + ni * 16 + l16;
          outF[(long)row * DH + c] = acc[mi][ni][r] + bias1[c];
        }
      } else {  // MODE 4: routed fc2 atomic fallback
        if (row < cnt_end) {
          const int t = slot_tok[row] >> 1;
          const float w = wts[row];            // slot_wt passed in wts param
#pragma unroll
          for (int ni = 0; ni < 4; ++ni) {
            const int c = ccol0 + ni * 16 + l16;
            atomicAdd(&outF[(long)t * DH + c], w * (acc[mi][ni][r] + bias[c]));
          }
        }
      }
    }
  }
}

// ---------------------------------------------------------------------------
extern "C" void kernel_launch(void* const* d_in, const int* in_sizes, int n_in,
                              void* d_out, int out_size, void* d_ws, size_t ws_size,
                              hipStream_t stream) {
  const float* x     = (const float*)d_in[0];
  const float* gw    = (const float*)d_in[1];
  const float* fc1w  = (const float*)d_in[2];
  const float* fc1bs = (const float*)d_in[3];
  const float* fc2w  = (const float*)d_in[4];
  const float* fc2bs = (const float*)d_in[5];
  const float* w1w   = (const float*)d_in[6];
  const float* w1bs  = (const float*)d_in[7];
  const float* w3w   = (const float*)d_in[8];
  const float* w3bs  = (const float*)d_in[9];
  const float* w2w   = (const float*)d_in[10];
  const float* w2bs  = (const float*)d_in[11];
  float* out = (float*)d_out;

  char* p = (char*)d_ws;
  auto take = [&](size_t b) { char* r = p; p += (b + 255) & ~(size_t)255; return r; };
  unsigned short* xb   = (unsigned short*)take((size_t)T_TOK * DH * 2);
  unsigned short* fc1b = (unsigned short*)take((size_t)NE * DF * DH * 2);
  unsigned short* fc2b = (unsigned short*)take((size_t)NE * DH * DF * 2);
  unsigned short* bint = (unsigned short*)take((size_t)2 * DF * DH * 2);  // w1/w3 zip
  unsigned short* w2b  = (unsigned short*)take((size_t)DH * DF * 2);
  unsigned short* h    = (unsigned short*)take((size_t)NROW_H * DF * 2);
  int*   eids     = (int*)take((size_t)NSLOT * 4);
  float* wts      = (float*)take((size_t)NSLOT * 4);
  int*   hcur     = (int*)take(NE * 64 * 4);
  int*   cur2     = (int*)take(NE * 64 * 4);
  int*   sched    = (int*)take(32 * 4);
  int*   slot_tok = (int*)take((size_t)NROW_H * 4);
  float* slot_wt  = (float*)take((size_t)NROW_H * 4);
  int*   slot_pos = (int*)take((size_t)NSLOT * 4);

  // path A extra: y rows [0,16384) alias fc1b (exactly 16384*768 bf16, dead
  // after routed fc1); rows [16384, NROW_H) get a dedicated region.
  const size_t yhi_bytes = (size_t)(NROW_H - YSPLIT) * DH * 2;
  const bool pathA = ((size_t)(p - (char*)d_ws) + yhi_bytes) <= ws_size;
  unsigned short* ylo = fc1b;
  unsigned short* yhi = pathA ? (unsigned short*)take(yhi_bytes) : nullptr;

  hipMemsetAsync(hcur, 0, NE * 64 * sizeof(int), stream);

  auto conv = [&](const float* s, unsigned short* d, long n) {
    int n4 = (int)(n >> 2);
    conv_f32_bf16<<<(n4 + 255) / 256, 256, 0, stream>>>(s, d, n4);
  };
  conv(fc1w, fc1b, (long)NE * DF * DH);
  conv(fc2w, fc2b, (long)NE * DH * DF);
  conv(w2w, w2b, (long)DH * DF);
  conv_interleave_k<<<2 * DF, 192, 0, stream>>>(w1w, w3w, bint);

  // gate: topk (no atomics) -> histogram -> scan -> scatter
  gate_topk<<<T_TOK / 4, 256, 0, stream>>>(x, gw, xb, eids, wts);
  hist_k<<<NSLOT / 256, 256, 0, stream>>>(eids, hcur);
  scan_k<<<1, 64, 0, stream>>>(hcur, sched, cur2);
  scatter_k<<<NSLOT / 256, 256, 0, stream>>>(eids, wts, cur2, slot_tok, slot_wt,
                                             slot_pos);

  if (pathA) {
    // routed fc1 -> routed fc2 (y rows) -> shared fc1 -> shared fc2+combine
    gemm8_k<1, DH, 8, 8 * MT_R><<<8 * MT_R, 512, 0, stream>>>(
        xb, fc1b, fc1bs, nullptr, nullptr, h,
        sched, slot_tok, nullptr, nullptr, nullptr, nullptr);
    gemm8_k<3, DF, 3, 3 * MT_R><<<3 * MT_R, 512, 0, stream>>>(
        h, fc2b, fc2bs, nullptr, nullptr, nullptr,
        sched, nullptr, nullptr, nullptr, ylo, yhi);
    gemm8_k<0, DH, 16, 1024><<<1024, 512, 0, stream>>>(
        xb, bint, w1bs, w3bs, nullptr, h,
        nullptr, nullptr, nullptr, nullptr, nullptr, nullptr);
    gemm8_k<2, DF, 3, 192><<<192, 512, 0, stream>>>(
        h, w2b, w2bs, nullptr, out, nullptr,
        nullptr, nullptr, slot_pos, wts, ylo, yhi);
  } else {
    // fallback: shared plain, routed atomic (no y aliasing needed)
    gemm8_k<0, DH, 16, 1024><<<1024, 512, 0, stream>>>(
        xb, bint, w1bs, w3bs, nullptr, h,
        nullptr, nullptr, nullptr, nullptr, nullptr, nullptr);
    gemm8_k<5, DF, 3, 192><<<192, 512, 0, stream>>>(
        h, w2b, w2bs, nullptr, out, nullptr,
        nullptr, nullptr, nullptr, nullptr, nullptr, nullptr);
    gemm8_k<1, DH, 8, 8 * MT_R><<<8 * MT_R, 512, 0, stream>>>(
        xb, fc1b, fc1bs, nullptr, nullptr, h,
        sched, slot_tok, nullptr, nullptr, nullptr, nullptr);
    gemm8_k<4, DF, 3, 3 * MT_R><<<3 * MT_R, 512, 0, stream>>>(
        h, fc2b, fc2bs, nullptr, out, nullptr,
        sched, slot_tok, nullptr, slot_wt, nullptr, nullptr);
  }
}

// Round 4
// 734.930 us; speedup vs baseline: 1.2909x; 1.2109x over previous
//
#include <hip/hip_runtime.h>
#include <math.h>

#define T_TOK 16384
#define DH 768
#define DF 2048
#define NE 8
#define NSLOT (2 * T_TOK)          // 32768 routed (token,slot) entries
#define MT_ROUTED 264              // ceil((NSLOT + 8*127)/128) m-tiles, worst case
#define NROW_H (MT_ROUTED * 128)   // 33792 rows in routed h / y buffers

typedef __attribute__((ext_vector_type(8))) short bf16x8;
typedef __attribute__((ext_vector_type(4))) float f32x4;

__device__ __forceinline__ unsigned short f2bf(float f) {
  union { float f; unsigned int u; } v; v.f = f;
  unsigned int u = v.u;
  u += 0x7fffu + ((u >> 16) & 1u);   // round-to-nearest-even
  return (unsigned short)(u >> 16);
}
__device__ __forceinline__ float bf2f(unsigned short s) {
  union { unsigned int u; float f; } v; v.u = ((unsigned int)s) << 16; return v.f;
}

__device__ __forceinline__ float gelu_exact(float x) {
  return 0.5f * x * (1.0f + erff(x * 0.70710678118654752440f));
}

// y buffer is split: rows [0,T_TOK) alias the dead fc1b region, rows
// [T_TOK, NROW_H) live in a small dedicated region (saves 25 MB of ws).
__device__ __forceinline__ unsigned short* yrow(unsigned short* ylo,
                                                unsigned short* yhi, int s) {
  return (s < T_TOK) ? (ylo + (long)s * DH) : (yhi + (long)(s - T_TOK) * DH);
}

// async global->LDS, 16B per lane; lds ptr must be wave-uniform (HW adds lane*16)
__device__ __forceinline__ void async_cp16(void* lds, const void* g) {
  __builtin_amdgcn_global_load_lds(
      (const __attribute__((address_space(1))) unsigned int*)(unsigned long long)g,
      (__attribute__((address_space(3))) unsigned int*)(unsigned int)(unsigned long long)lds,
      16, 0, 0);
}

// ---------------------------------------------------------------------------
__global__ __launch_bounds__(256) void conv_f32_bf16(
    const float* __restrict__ src, unsigned short* __restrict__ dst, int n4) {
  int i = blockIdx.x * blockDim.x + threadIdx.x;
  if (i >= n4) return;
  const float4 v = ((const float4*)src)[i];
  union { unsigned short us[4]; unsigned long long u64; } o;
  o.us[0] = f2bf(v.x); o.us[1] = f2bf(v.y); o.us[2] = f2bf(v.z); o.us[3] = f2bf(v.w);
  ((unsigned long long*)dst)[i] = o.u64;
}

// ---------------------------------------------------------------------------
// gate phase A: per-token logits (fp32), top-2, renorm weights. NO atomics.
__global__ __launch_bounds__(256) void gate_topk(
    const float* __restrict__ x, const float* __restrict__ gw,
    unsigned short* __restrict__ xb, int* __restrict__ eids,
    float* __restrict__ wts) {
  const int wave = threadIdx.x >> 6;
  const int lane = threadIdx.x & 63;
  const int t = blockIdx.x * 4 + wave;
  float4 xv[3];
#pragma unroll
  for (int i = 0; i < 3; ++i) {
    const int c = i * 256 + lane * 4;
    xv[i] = *(const float4*)&x[(long)t * DH + c];
    ushort4 o;
    o.x = f2bf(xv[i].x); o.y = f2bf(xv[i].y);
    o.z = f2bf(xv[i].z); o.w = f2bf(xv[i].w);
    *(ushort4*)&xb[(long)t * DH + c] = o;
  }
  float s[NE];
#pragma unroll
  for (int e = 0; e < NE; ++e) {
    float a = 0.f;
#pragma unroll
    for (int i = 0; i < 3; ++i) {
      const float4 g = *(const float4*)&gw[e * DH + i * 256 + lane * 4];
      a += xv[i].x * g.x + xv[i].y * g.y + xv[i].z * g.z + xv[i].w * g.w;
    }
    s[e] = a;
  }
#pragma unroll
  for (int off = 32; off >= 1; off >>= 1) {
#pragma unroll
    for (int e = 0; e < NE; ++e) s[e] += __shfl_xor(s[e], off);
  }
  if (lane == 0) {
    float b1 = s[0]; int i1 = 0;
#pragma unroll
    for (int e = 1; e < NE; ++e) { if (s[e] > b1) { b1 = s[e]; i1 = e; } }
    float b2 = -3.4e38f; int i2 = 0;
#pragma unroll
    for (int e = 0; e < NE; ++e) {
      if (e != i1 && s[e] > b2) { b2 = s[e]; i2 = e; }
    }
    const float ex = expf(b2 - b1);
    eids[2 * t]     = i1; wts[2 * t]     = 1.f / (1.f + ex);
    eids[2 * t + 1] = i2; wts[2 * t + 1] = ex / (1.f + ex);
  }
}

// gate phase B: histogram with ballot aggregation; counters padded 256B apart
__global__ __launch_bounds__(256) void hist_k(
    const int* __restrict__ eids, int* __restrict__ hcur) {
  const int j = blockIdx.x * 256 + threadIdx.x;
  const int lane = threadIdx.x & 63;
  const int eid = eids[j];
#pragma unroll
  for (int e = 0; e < NE; ++e) {
    const unsigned long long m = __ballot(eid == e);
    const int tot = __popcll(m);
    if (tot && lane == (__ffsll((long long)m) - 1)) atomicAdd(&hcur[e * 64], tot);
  }
}

// gate phase C: exclusive scan of 128-padded counts
__global__ void scan_k(const int* __restrict__ hcur, int* __restrict__ sched,
                       int* __restrict__ cur2) {
  if (threadIdx.x == 0) {
    int b = 0;
#pragma unroll
    for (int e = 0; e < NE; ++e) {
      const int c = hcur[e * 64];
      sched[e] = b; sched[9 + e] = c; cur2[e * 64] = b;
      b += (c + 127) & ~127;
    }
    sched[8] = b;
  }
}

// gate phase D: scatter into compacted per-expert slots + inverse map
__global__ __launch_bounds__(256) void scatter_k(
    const int* __restrict__ eids, const float* __restrict__ wts,
    int* __restrict__ cur2, int* __restrict__ slot_tok,
    float* __restrict__ slot_wt, int* __restrict__ slot_pos) {
  const int j = blockIdx.x * 256 + threadIdx.x;
  const int lane = threadIdx.x & 63;
  const int eid = eids[j];
  const float w = wts[j];
#pragma unroll
  for (int e = 0; e < NE; ++e) {
    const unsigned long long m = __ballot(eid == e);
    const int tot = __popcll(m);
    if (!tot) continue;                      // wave-uniform branch
    const int leader = __ffsll((long long)m) - 1;
    int b = 0;
    if (lane == leader) b = atomicAdd(&cur2[e * 64], tot);
    b = __shfl(b, leader);
    if (eid == e) {
      const int pos = b + __popcll(m & ((1ull << lane) - 1));
      slot_tok[pos] = j;                     // token = j>>1
      slot_wt[pos] = w;
      slot_pos[j] = pos;                     // inverse map for combine
    }
  }
}

// ---------------------------------------------------------------------------
// 128x128 bf16 MFMA GEMM, C = A[MxK] @ W[NxK]^T. XCD-swizzled 1D grid:
// yx = (id%8)*BPX + id/8; x = yx%GX (n-tile, fastest within an XCD -> A-tile
// L2 reuse), y = yx/GX (m-tile).
// Round-4 changes vs the proven 745us version (both proven on HW in r3):
//  (1) T2 LDS chunk swizzle (r3-measured conflict count: 0 with identical
//      64B-row/4-chunk geometry): stage with pre-permuted GLOBAL source chunk
//      (lane&3)^((lane>>3)&3), linear LDS dest (rule 21); ds_read at chunk
//      quad ^ ((l16>>1)&3).
//  (2) double-buffered LDS + single __syncthreads per K-step: stage(next)
//      issued BEFORE compute(cur); the barrier's vmcnt(0) drain lands a full
//      MFMA phase (~600+ cyc) after load issue instead of immediately.
//  MODE 0: shared fc1 dual-B: h = gelu(A@B1^T+b1)*(A@B2^T+b3) -> outH (bf16)
//  MODE 1: routed fc1 (all experts), A rows gathered via slot_tok -> outH
//  MODE 2: shared fc2 + combine: out = acc+b + w0*y[s0]+w1*y[s1] (plain store)
//  MODE 3: routed fc2 (all experts): y[slot] = acc + b (bf16, plain store)
//  MODE 4: routed fc2 (all experts): atomicAdd(out[tok], w*(acc+b))  [fallback]
//  MODE 5: shared fc2 plain: out = acc + b                           [fallback]
template <int MODE, int GX, int GTOT>
__global__ __launch_bounds__(256, 2) void gemm_k(
    const unsigned short* __restrict__ A, const unsigned short* __restrict__ B1,
    const unsigned short* __restrict__ B2, const float* __restrict__ bias1,
    const float* __restrict__ bias2, float* __restrict__ outF,
    unsigned short* __restrict__ outH, int K,
    const int* __restrict__ sched, const int* __restrict__ slot_tok,
    const int* __restrict__ slot_pos, const float* __restrict__ wts,
    unsigned short* __restrict__ ylo, unsigned short* __restrict__ yhi) {
  constexpr int BPX = (GTOT + 7) / 8;
  const int id = blockIdx.x;
  const int yx = (id & 7) * BPX + (id >> 3);
  const int n0 = (yx % GX) * 128;
  const int m0 = (yx / GX) * 128;

  const int tid = threadIdx.x;
  const int wave = tid >> 6;
  const int lane = tid & 63;
  const int wm = wave >> 1, wn = wave & 1;
  const int l16 = lane & 15, quad = lane >> 4;

  const unsigned short* Bbase = B1;
  const float* bias = bias1;
  int cnt_end = 0;
  if constexpr (MODE == 1 || MODE == 3 || MODE == 4) {
    if (m0 >= sched[8]) return;              // block-uniform exit, no barriers yet
    int e = 0;
#pragma unroll
    for (int i = 1; i < NE; ++i) { if (m0 >= sched[i]) e = i; }
    cnt_end = sched[e] + sched[9 + e];       // base[e] + count[e]
    Bbase = B1 + (long)e * ((long)DF * DH);  // fc1[e] and fc2[e] are both DF*DH
    bias = bias1 + e * ((MODE == 1) ? DF : DH);
  }

  __shared__ __align__(16) unsigned short As[2][128 * 32];
  __shared__ __align__(16) unsigned short Bs[2][128 * 32];
  __shared__ __align__(16) unsigned short Cs[(MODE == 0) ? 2 : 1]
                                            [(MODE == 0) ? 128 * 32 : 16];

  const int srow0 = wave * 16 + (lane >> 2);
  const int srow1 = 64 + srow0;
  // T2: pre-permuted global source chunk; LDS dest stays linear (rule 21).
  // staging row-in-16 = lane>>2 -> key = (lane>>3)&3  (r3-proven, 0 conflicts)
  const int scol = (((lane & 3) ^ ((lane >> 3) & 3)) << 3);

  long ar0, ar1;
  if constexpr (MODE == 1) {
    const int p0 = m0 + srow0, p1 = m0 + srow1;
    const int t0 = (p0 < cnt_end) ? (slot_tok[p0] >> 1) : 0;
    const int t1 = (p1 < cnt_end) ? (slot_tok[p1] >> 1) : 0;
    ar0 = (long)t0 * K; ar1 = (long)t1 * K;
  } else {
    ar0 = (long)(m0 + srow0) * K;
    ar1 = (long)(m0 + srow1) * K;
  }
  const unsigned short* ap0 = A + ar0 + scol;
  const unsigned short* ap1 = A + ar1 + scol;
  const unsigned short* bp0 = Bbase + (long)(n0 + srow0) * K + scol;
  const unsigned short* bp1 = Bbase + (long)(n0 + srow1) * K + scol;
  const unsigned short* cp0 = nullptr; const unsigned short* cp1 = nullptr;
  if constexpr (MODE == 0) {
    cp0 = B2 + (long)(n0 + srow0) * K + scol;
    cp1 = B2 + (long)(n0 + srow1) * K + scol;
  }

  const int woff = wave * 512;

  f32x4 acc[4][4];
  f32x4 acc2[(MODE == 0) ? 4 : 1][(MODE == 0) ? 4 : 1];
#pragma unroll
  for (int i = 0; i < 4; ++i) {
#pragma unroll
    for (int j = 0; j < 4; ++j) {
      acc[i][j] = {0.f, 0.f, 0.f, 0.f};
      if constexpr (MODE == 0) acc2[i][j] = {0.f, 0.f, 0.f, 0.f};
    }
  }

  auto stage = [&](int b, int kt) {
    const int ko = kt << 5;
    async_cp16(&As[b][woff],        ap0 + ko);
    async_cp16(&As[b][woff + 2048], ap1 + ko);
    async_cp16(&Bs[b][woff],        bp0 + ko);
    async_cp16(&Bs[b][woff + 2048], bp1 + ko);
    if constexpr (MODE == 0) {
      async_cp16(&Cs[b][woff],        cp0 + ko);
      async_cp16(&Cs[b][woff + 2048], cp1 + ko);
    }
  };

  // T2 read-side: swizzled chunk (elements); read row-in-16 = l16
  const int rchunk = ((quad ^ ((l16 >> 1) & 3)) << 3);

  const int KT = K >> 5;
  stage(0, 0);
  __syncthreads();                           // drains prologue loads (vmcnt 0)

  for (int kt = 0; kt < KT; ++kt) {
    const int b = kt & 1;
    if (kt + 1 < KT) stage(b ^ 1, kt + 1);   // prefetch next K-step first

    bf16x8 af[4], bfr[4], cfr[(MODE == 0) ? 4 : 1];
#pragma unroll
    for (int mi = 0; mi < 4; ++mi)
      af[mi] = *(const bf16x8*)&As[b][(wm * 64 + mi * 16 + l16) * 32 + rchunk];
#pragma unroll
    for (int ni = 0; ni < 4; ++ni) {
      bfr[ni] = *(const bf16x8*)&Bs[b][(wn * 64 + ni * 16 + l16) * 32 + rchunk];
      if constexpr (MODE == 0)
        cfr[ni] = *(const bf16x8*)&Cs[b][(wn * 64 + ni * 16 + l16) * 32 + rchunk];
    }
#pragma unroll
    for (int mi = 0; mi < 4; ++mi) {
#pragma unroll
      for (int ni = 0; ni < 4; ++ni) {
        acc[mi][ni] = __builtin_amdgcn_mfma_f32_16x16x32_bf16(
            af[mi], bfr[ni], acc[mi][ni], 0, 0, 0);
        if constexpr (MODE == 0)
          acc2[mi][ni] = __builtin_amdgcn_mfma_f32_16x16x32_bf16(
              af[mi], cfr[ni], acc2[mi][ni], 0, 0, 0);
      }
    }
    __syncthreads();   // one barrier/K-step: WAR on buf b + drains buf b^1 loads
  }

  // epilogue; C/D layout: row = quad*4 + reg, col = lane&15 (m89-verified)
#pragma unroll
  for (int mi = 0; mi < 4; ++mi) {
#pragma unroll
    for (int r = 0; r < 4; ++r) {
      const int row = m0 + wm * 64 + mi * 16 + quad * 4 + r;
      if constexpr (MODE == 3) {
        unsigned short* yr = yrow(ylo, yhi, row);
#pragma unroll
        for (int ni = 0; ni < 4; ++ni) {
          const int c = n0 + wn * 64 + ni * 16 + l16;
          yr[c] = f2bf(acc[mi][ni][r] + bias[c]);
        }
      } else if constexpr (MODE == 4) {
        if (row < cnt_end) {
          const int t = slot_tok[row] >> 1;
          const float w = wts[row];            // slot_wt passed in wts param
#pragma unroll
          for (int ni = 0; ni < 4; ++ni) {
            const int c = n0 + wn * 64 + ni * 16 + l16;
            atomicAdd(&outF[(long)t * DH + c], w * (acc[mi][ni][r] + bias[c]));
          }
        }
      } else if constexpr (MODE == 2) {
        const int s0 = slot_pos[2 * row], s1 = slot_pos[2 * row + 1];
        const float w0 = wts[2 * row], w1 = wts[2 * row + 1];
        const unsigned short* y0 = yrow(ylo, yhi, s0);
        const unsigned short* y1 = yrow(ylo, yhi, s1);
#pragma unroll
        for (int ni = 0; ni < 4; ++ni) {
          const int c = n0 + wn * 64 + ni * 16 + l16;
          outF[(long)row * DH + c] =
              acc[mi][ni][r] + bias[c] + w0 * bf2f(y0[c]) + w1 * bf2f(y1[c]);
        }
      } else if constexpr (MODE == 5) {
#pragma unroll
        for (int ni = 0; ni < 4; ++ni) {
          const int c = n0 + wn * 64 + ni * 16 + l16;
          outF[(long)row * DH + c] = acc[mi][ni][r] + bias[c];
        }
      } else if constexpr (MODE == 1) {
#pragma unroll
        for (int ni = 0; ni < 4; ++ni) {
          const int c = n0 + wn * 64 + ni * 16 + l16;
          outH[(long)row * DF + c] = f2bf(gelu_exact(acc[mi][ni][r] + bias[c]));
        }
      } else {
#pragma unroll
        for (int ni = 0; ni < 4; ++ni) {
          const int c = n0 + wn * 64 + ni * 16 + l16;
          const float h1 = acc[mi][ni][r] + bias[c];
          const float h3 = acc2[mi][ni][r] + bias2[c];
          outH[(long)row * DF + c] = f2bf(gelu_exact(h1) * h3);
        }
      }
    }
  }
}

// ---------------------------------------------------------------------------
extern "C" void kernel_launch(void* const* d_in, const int* in_sizes, int n_in,
                              void* d_out, int out_size, void* d_ws, size_t ws_size,
                              hipStream_t stream) {
  const float* x     = (const float*)d_in[0];
  const float* gw    = (const float*)d_in[1];
  const float* fc1w  = (const float*)d_in[2];
  const float* fc1bs = (const float*)d_in[3];
  const float* fc2w  = (const float*)d_in[4];
  const float* fc2bs = (const float*)d_in[5];
  const float* w1w   = (const float*)d_in[6];
  const float* w1bs  = (const float*)d_in[7];
  const float* w3w   = (const float*)d_in[8];
  const float* w3bs  = (const float*)d_in[9];
  const float* w2w   = (const float*)d_in[10];
  const float* w2bs  = (const float*)d_in[11];
  float* out = (float*)d_out;

  char* p = (char*)d_ws;
  auto take = [&](size_t b) { char* r = p; p += (b + 255) & ~(size_t)255; return r; };
  unsigned short* xb   = (unsigned short*)take((size_t)T_TOK * DH * 2);
  unsigned short* fc1b = (unsigned short*)take((size_t)NE * DF * DH * 2);
  unsigned short* fc2b = (unsigned short*)take((size_t)NE * DH * DF * 2);
  unsigned short* w1b  = (unsigned short*)take((size_t)DF * DH * 2);
  unsigned short* w3b  = (unsigned short*)take((size_t)DF * DH * 2);
  unsigned short* w2b  = (unsigned short*)take((size_t)DH * DF * 2);
  unsigned short* h    = (unsigned short*)take((size_t)NROW_H * DF * 2);
  int*   eids     = (int*)take((size_t)NSLOT * 4);
  float* wts      = (float*)take((size_t)NSLOT * 4);
  int*   hcur     = (int*)take(NE * 64 * 4);
  int*   cur2     = (int*)take(NE * 64 * 4);
  int*   sched    = (int*)take(32 * 4);
  int*   slot_tok = (int*)take((size_t)NROW_H * 4);
  float* slot_wt  = (float*)take((size_t)NROW_H * 4);
  int*   slot_pos = (int*)take((size_t)NSLOT * 4);
  // common footprint: ~224.4e6 B (round-2-proven size)

  // path A extra: high rows of the routed-y buffer; low rows alias fc1b,
  // which is dead after routed fc1 (stream-ordered before routed fc2 writes y)
  const size_t yhi_bytes = (size_t)(NROW_H - T_TOK) * DH * 2;
  const bool pathA = ((size_t)(p - (char*)d_ws) + yhi_bytes) <= ws_size;
  unsigned short* ylo = fc1b;
  unsigned short* yhi = pathA ? (unsigned short*)take(yhi_bytes) : nullptr;

  hipMemsetAsync(hcur, 0, NE * 64 * sizeof(int), stream);

  auto conv = [&](const float* s, unsigned short* d, long n) {
    int n4 = (int)(n >> 2);
    conv_f32_bf16<<<(n4 + 255) / 256, 256, 0, stream>>>(s, d, n4);
  };
  conv(fc1w, fc1b, (long)NE * DF * DH);
  conv(fc2w, fc2b, (long)NE * DH * DF);
  conv(w1w, w1b, (long)DF * DH);
  conv(w3w, w3b, (long)DF * DH);
  conv(w2w, w2b, (long)DH * DF);

  // gate: topk (no atomics) -> histogram -> scan -> scatter
  gate_topk<<<T_TOK / 4, 256, 0, stream>>>(x, gw, xb, eids, wts);
  hist_k<<<NSLOT / 256, 256, 0, stream>>>(eids, hcur);
  scan_k<<<1, 64, 0, stream>>>(hcur, sched, cur2);
  scatter_k<<<NSLOT / 256, 256, 0, stream>>>(eids, wts, cur2, slot_tok, slot_wt,
                                             slot_pos);

  if (pathA) {
    // routed fc1 -> routed fc2 (y rows) -> shared fc1 -> shared fc2+combine
    gemm_k<1, 16, 16 * MT_ROUTED><<<16 * MT_ROUTED, 256, 0, stream>>>(
        xb, fc1b, nullptr, fc1bs, nullptr, nullptr, h, DH,
        sched, slot_tok, nullptr, nullptr, nullptr, nullptr);
    gemm_k<3, 6, 6 * MT_ROUTED><<<6 * MT_ROUTED, 256, 0, stream>>>(
        h, fc2b, nullptr, fc2bs, nullptr, nullptr, nullptr, DF,
        sched, nullptr, nullptr, nullptr, ylo, yhi);
    gemm_k<0, 16, 16 * (T_TOK / 128)><<<16 * (T_TOK / 128), 256, 0, stream>>>(
        xb, w1b, w3b, w1bs, w3bs, nullptr, h, DH,
        nullptr, nullptr, nullptr, nullptr, nullptr, nullptr);
    gemm_k<2, 6, 6 * (T_TOK / 128)><<<6 * (T_TOK / 128), 256, 0, stream>>>(
        h, w2b, nullptr, w2bs, nullptr, out, nullptr, DF,
        nullptr, nullptr, slot_pos, wts, ylo, yhi);
  } else {
    // fallback (round-2-proven footprint/order): shared plain, routed atomic
    gemm_k<0, 16, 16 * (T_TOK / 128)><<<16 * (T_TOK / 128), 256, 0, stream>>>(
        xb, w1b, w3b, w1bs, w3bs, nullptr, h, DH,
        nullptr, nullptr, nullptr, nullptr, nullptr, nullptr);
    gemm_k<5, 6, 6 * (T_TOK / 128)><<<6 * (T_TOK / 128), 256, 0, stream>>>(
        h, w2b, nullptr, w2bs, nullptr, out, nullptr, DF,
        nullptr, nullptr, nullptr, nullptr, nullptr, nullptr);
    gemm_k<1, 16, 16 * MT_ROUTED><<<16 * MT_ROUTED, 256, 0, stream>>>(
        xb, fc1b, nullptr, fc1bs, nullptr, nullptr, h, DH,
        sched, slot_tok, nullptr, nullptr, nullptr, nullptr);
    gemm_k<4, 6, 6 * MT_ROUTED><<<6 * MT_ROUTED, 256, 0, stream>>>(
        h, fc2b, nullptr, fc2bs, nullptr, out, nullptr, DF,
        sched, slot_tok, nullptr, slot_wt, nullptr, nullptr);
  }
}

// Round 5
// 722.015 us; speedup vs baseline: 1.3140x; 1.0179x over previous
//
#include <hip/hip_runtime.h>
#include <math.h>

#define T_TOK 16384
#define DH 768
#define DF 2048
#define NE 8
#define NSLOT (2 * T_TOK)          // 32768 routed (token,slot) entries
#define MT_ROUTED 264              // ceil((NSLOT + 8*127)/128) m-tiles, worst case
#define NROW_H (MT_ROUTED * 128)   // 33792 rows in routed h / y buffers

typedef __attribute__((ext_vector_type(8))) short bf16x8;
typedef __attribute__((ext_vector_type(4))) float f32x4;

__device__ __forceinline__ unsigned short f2bf(float f) {
  union { float f; unsigned int u; } v; v.f = f;
  unsigned int u = v.u;
  u += 0x7fffu + ((u >> 16) & 1u);   // round-to-nearest-even
  return (unsigned short)(u >> 16);
}
__device__ __forceinline__ float bf2f(unsigned short s) {
  union { unsigned int u; float f; } v; v.u = ((unsigned int)s) << 16; return v.f;
}

#if __has_builtin(__builtin_amdgcn_rcpf)
#define RCPF(x) __builtin_amdgcn_rcpf(x)
#else
#define RCPF(x) (1.0f / (x))
#endif
#if __has_builtin(__builtin_amdgcn_exp2f)
#define EXP2F(x) __builtin_amdgcn_exp2f(x)
#else
#define EXP2F(x) exp2f(x)
#endif

// gelu via Abramowitz-Stegun 7.1.26 erf (max abs err 1.5e-7, branch-free:
// ~16 VALU ops vs ~30 for libm erff). Error is far below bf16 rounding of h.
__device__ __forceinline__ float gelu_fast(float x) {
  const float z = 0.70710678118654752440f * x;
  const float a = fabsf(z);
  const float t = RCPF(fmaf(0.3275911f, a, 1.0f));
  float p = fmaf(1.061405429f, t, -1.453152027f);
  p = fmaf(p, t, 1.421413741f);
  p = fmaf(p, t, -0.284496736f);
  p = fmaf(p, t, 0.254829592f);
  p = p * t;
  const float e = EXP2F(z * z * -1.4426950408889634f);   // exp(-z^2)
  const float erfa = fmaf(-p, e, 1.0f);                  // erf(|z|)
  const float erfz = copysignf(erfa, z);
  return 0.5f * x * (1.0f + erfz);
}

// y buffer is split: rows [0,T_TOK) alias the dead fc1b region, rows
// [T_TOK, NROW_H) live in a small dedicated region (saves 25 MB of ws).
__device__ __forceinline__ unsigned short* yrow(unsigned short* ylo,
                                                unsigned short* yhi, int s) {
  return (s < T_TOK) ? (ylo + (long)s * DH) : (yhi + (long)(s - T_TOK) * DH);
}

// async global->LDS, 16B per lane; lds ptr must be wave-uniform (HW adds lane*16)
__device__ __forceinline__ void async_cp16(void* lds, const void* g) {
  __builtin_amdgcn_global_load_lds(
      (const __attribute__((address_space(1))) unsigned int*)(unsigned long long)g,
      (__attribute__((address_space(3))) unsigned int*)(unsigned int)(unsigned long long)lds,
      16, 0, 0);
}

// ---------------------------------------------------------------------------
__global__ __launch_bounds__(256) void conv_f32_bf16(
    const float* __restrict__ src, unsigned short* __restrict__ dst, int n4) {
  int i = blockIdx.x * blockDim.x + threadIdx.x;
  if (i >= n4) return;
  const float4 v = ((const float4*)src)[i];
  union { unsigned short us[4]; unsigned long long u64; } o;
  o.us[0] = f2bf(v.x); o.us[1] = f2bf(v.y); o.us[2] = f2bf(v.z); o.us[3] = f2bf(v.w);
  ((unsigned long long*)dst)[i] = o.u64;
}

// interleave w1/w3 rows 16-by-16 into bint[4096][768] bf16:
// h-col c=q*16+t -> w1 row c at bint[q*32+t], w3 row c at bint[q*32+16+t]
// (epilogue pairing of this layout harness-verified in rounds 2-3)
__global__ __launch_bounds__(192) void conv_interleave_k(
    const float* __restrict__ w1, const float* __restrict__ w3,
    unsigned short* __restrict__ dst) {
  const int row = blockIdx.x;           // 0..4095
  const int q = row >> 5, s = row & 31;
  const float* src = (s < 16) ? &w1[(long)(q * 16 + s) * DH]
                              : &w3[(long)(q * 16 + (s - 16)) * DH];
  const int c = threadIdx.x * 4;
  const float4 v = *(const float4*)&src[c];
  ushort4 o;
  o.x = f2bf(v.x); o.y = f2bf(v.y); o.z = f2bf(v.z); o.w = f2bf(v.w);
  *(ushort4*)&dst[(long)row * DH + c] = o;
}

// ---------------------------------------------------------------------------
// gate phase A: per-token logits (fp32), top-2, renorm weights. NO atomics.
__global__ __launch_bounds__(256) void gate_topk(
    const float* __restrict__ x, const float* __restrict__ gw,
    unsigned short* __restrict__ xb, int* __restrict__ eids,
    float* __restrict__ wts) {
  const int wave = threadIdx.x >> 6;
  const int lane = threadIdx.x & 63;
  const int t = blockIdx.x * 4 + wave;
  float4 xv[3];
#pragma unroll
  for (int i = 0; i < 3; ++i) {
    const int c = i * 256 + lane * 4;
    xv[i] = *(const float4*)&x[(long)t * DH + c];
    ushort4 o;
    o.x = f2bf(xv[i].x); o.y = f2bf(xv[i].y);
    o.z = f2bf(xv[i].z); o.w = f2bf(xv[i].w);
    *(ushort4*)&xb[(long)t * DH + c] = o;
  }
  float s[NE];
#pragma unroll
  for (int e = 0; e < NE; ++e) {
    float a = 0.f;
#pragma unroll
    for (int i = 0; i < 3; ++i) {
      const float4 g = *(const float4*)&gw[e * DH + i * 256 + lane * 4];
      a += xv[i].x * g.x + xv[i].y * g.y + xv[i].z * g.z + xv[i].w * g.w;
    }
    s[e] = a;
  }
#pragma unroll
  for (int off = 32; off >= 1; off >>= 1) {
#pragma unroll
    for (int e = 0; e < NE; ++e) s[e] += __shfl_xor(s[e], off);
  }
  if (lane == 0) {
    float b1 = s[0]; int i1 = 0;
#pragma unroll
    for (int e = 1; e < NE; ++e) { if (s[e] > b1) { b1 = s[e]; i1 = e; } }
    float b2 = -3.4e38f; int i2 = 0;
#pragma unroll
    for (int e = 0; e < NE; ++e) {
      if (e != i1 && s[e] > b2) { b2 = s[e]; i2 = e; }
    }
    const float ex = expf(b2 - b1);
    eids[2 * t]     = i1; wts[2 * t]     = 1.f / (1.f + ex);
    eids[2 * t + 1] = i2; wts[2 * t + 1] = ex / (1.f + ex);
  }
}

// gate phase B: histogram with ballot aggregation; counters padded 256B apart
__global__ __launch_bounds__(256) void hist_k(
    const int* __restrict__ eids, int* __restrict__ hcur) {
  const int j = blockIdx.x * 256 + threadIdx.x;
  const int lane = threadIdx.x & 63;
  const int eid = eids[j];
#pragma unroll
  for (int e = 0; e < NE; ++e) {
    const unsigned long long m = __ballot(eid == e);
    const int tot = __popcll(m);
    if (tot && lane == (__ffsll((long long)m) - 1)) atomicAdd(&hcur[e * 64], tot);
  }
}

// gate phase C: exclusive scan of 128-padded counts
__global__ void scan_k(const int* __restrict__ hcur, int* __restrict__ sched,
                       int* __restrict__ cur2) {
  if (threadIdx.x == 0) {
    int b = 0;
#pragma unroll
    for (int e = 0; e < NE; ++e) {
      const int c = hcur[e * 64];
      sched[e] = b; sched[9 + e] = c; cur2[e * 64] = b;
      b += (c + 127) & ~127;
    }
    sched[8] = b;
  }
}

// gate phase D: scatter into compacted per-expert slots + inverse map
__global__ __launch_bounds__(256) void scatter_k(
    const int* __restrict__ eids, const float* __restrict__ wts,
    int* __restrict__ cur2, int* __restrict__ slot_tok,
    float* __restrict__ slot_wt, int* __restrict__ slot_pos) {
  const int j = blockIdx.x * 256 + threadIdx.x;
  const int lane = threadIdx.x & 63;
  const int eid = eids[j];
  const float w = wts[j];
#pragma unroll
  for (int e = 0; e < NE; ++e) {
    const unsigned long long m = __ballot(eid == e);
    const int tot = __popcll(m);
    if (!tot) continue;                      // wave-uniform branch
    const int leader = __ffsll((long long)m) - 1;
    int b = 0;
    if (lane == leader) b = atomicAdd(&cur2[e * 64], tot);
    b = __shfl(b, leader);
    if (eid == e) {
      const int pos = b + __popcll(m & ((1ull << lane) - 1));
      slot_tok[pos] = j;                     // token = j>>1
      slot_wt[pos] = w;
      slot_pos[j] = pos;                     // inverse map for combine
    }
  }
}

// ---------------------------------------------------------------------------
// 128x128 bf16 MFMA GEMM, C = A[MxK] @ W[NxK]^T. XCD-swizzled 1D grid:
// yx = (id%8)*BPX + id/8; x = yx%GX (n-tile, fastest within an XCD -> A-tile
// L2 reuse), y = yx/GX (m-tile).
// Proven-in-r4: T2 LDS chunk swizzle (conflicts == 0 measured) + double-buffer
// with one __syncthreads per K-step (stage(next) issued before compute(cur)).
// Round-5: fast-erf gelu epilogue (VALU tail was 55% busy vs MFMA 27%);
// MODE 0 now uses interleaved bint (single B, 32KB LDS like other modes).
//  MODE 0: shared fc1, bint: h = gelu(a@w1+b1)*(a@w3+b3) -> outH (bf16)
//  MODE 1: routed fc1 (all experts), A rows gathered via slot_tok -> outH
//  MODE 2: shared fc2 + combine: out = acc+b + w0*y[s0]+w1*y[s1] (plain store)
//  MODE 3: routed fc2 (all experts): y[slot] = acc + b (bf16, plain store)
//  MODE 4: routed fc2 (all experts): atomicAdd(out[tok], w*(acc+b))  [fallback]
//  MODE 5: shared fc2 plain: out = acc + b                           [fallback]
template <int MODE, int GX, int GTOT>
__global__ __launch_bounds__(256, 2) void gemm_k(
    const unsigned short* __restrict__ A, const unsigned short* __restrict__ B1,
    const float* __restrict__ bias1, const float* __restrict__ bias2,
    float* __restrict__ outF, unsigned short* __restrict__ outH, int K,
    const int* __restrict__ sched, const int* __restrict__ slot_tok,
    const int* __restrict__ slot_pos, const float* __restrict__ wts,
    unsigned short* __restrict__ ylo, unsigned short* __restrict__ yhi) {
  constexpr int BPX = (GTOT + 7) / 8;
  const int id = blockIdx.x;
  const int yx = (id & 7) * BPX + (id >> 3);
  const int n0 = (yx % GX) * 128;
  const int m0 = (yx / GX) * 128;

  const int tid = threadIdx.x;
  const int wave = tid >> 6;
  const int lane = tid & 63;
  const int wm = wave >> 1, wn = wave & 1;
  const int l16 = lane & 15, quad = lane >> 4;

  const unsigned short* Bbase = B1;
  const float* bias = bias1;
  int cnt_end = 0;
  if constexpr (MODE == 1 || MODE == 3 || MODE == 4) {
    if (m0 >= sched[8]) return;              // block-uniform exit, no barriers yet
    int e = 0;
#pragma unroll
    for (int i = 1; i < NE; ++i) { if (m0 >= sched[i]) e = i; }
    cnt_end = sched[e] + sched[9 + e];       // base[e] + count[e]
    Bbase = B1 + (long)e * ((long)DF * DH);  // fc1[e] and fc2[e] are both DF*DH
    bias = bias1 + e * ((MODE == 1) ? DF : DH);
  }

  __shared__ __align__(16) unsigned short As[2][128 * 32];
  __shared__ __align__(16) unsigned short Bs[2][128 * 32];

  const int srow0 = wave * 16 + (lane >> 2);
  const int srow1 = 64 + srow0;
  // T2: pre-permuted global source chunk; LDS dest stays linear (rule 21).
  // staging row-in-16 = lane>>2 -> key = (lane>>3)&3  (r4-proven, 0 conflicts)
  const int scol = (((lane & 3) ^ ((lane >> 3) & 3)) << 3);

  long ar0, ar1;
  if constexpr (MODE == 1) {
    const int p0 = m0 + srow0, p1 = m0 + srow1;
    const int t0 = (p0 < cnt_end) ? (slot_tok[p0] >> 1) : 0;
    const int t1 = (p1 < cnt_end) ? (slot_tok[p1] >> 1) : 0;
    ar0 = (long)t0 * K; ar1 = (long)t1 * K;
  } else {
    ar0 = (long)(m0 + srow0) * K;
    ar1 = (long)(m0 + srow1) * K;
  }
  const unsigned short* ap0 = A + ar0 + scol;
  const unsigned short* ap1 = A + ar1 + scol;
  const unsigned short* bp0 = Bbase + (long)(n0 + srow0) * K + scol;
  const unsigned short* bp1 = Bbase + (long)(n0 + srow1) * K + scol;

  const int woff = wave * 512;

  f32x4 acc[4][4];
#pragma unroll
  for (int i = 0; i < 4; ++i)
#pragma unroll
    for (int j = 0; j < 4; ++j) acc[i][j] = {0.f, 0.f, 0.f, 0.f};

  auto stage = [&](int b, int kt) {
    const int ko = kt << 5;
    async_cp16(&As[b][woff],        ap0 + ko);
    async_cp16(&As[b][woff + 2048], ap1 + ko);
    async_cp16(&Bs[b][woff],        bp0 + ko);
    async_cp16(&Bs[b][woff + 2048], bp1 + ko);
  };

  // T2 read-side: swizzled chunk (elements); read row-in-16 = l16
  const int rchunk = ((quad ^ ((l16 >> 1) & 3)) << 3);

  const int KT = K >> 5;
  stage(0, 0);
  __syncthreads();                           // drains prologue loads (vmcnt 0)

  for (int kt = 0; kt < KT; ++kt) {
    const int b = kt & 1;
    if (kt + 1 < KT) stage(b ^ 1, kt + 1);   // prefetch next K-step first

    bf16x8 af[4], bfr[4];
#pragma unroll
    for (int mi = 0; mi < 4; ++mi)
      af[mi] = *(const bf16x8*)&As[b][(wm * 64 + mi * 16 + l16) * 32 + rchunk];
#pragma unroll
    for (int ni = 0; ni < 4; ++ni)
      bfr[ni] = *(const bf16x8*)&Bs[b][(wn * 64 + ni * 16 + l16) * 32 + rchunk];
#pragma unroll
    for (int mi = 0; mi < 4; ++mi) {
#pragma unroll
      for (int ni = 0; ni < 4; ++ni) {
        acc[mi][ni] = __builtin_amdgcn_mfma_f32_16x16x32_bf16(
            af[mi], bfr[ni], acc[mi][ni], 0, 0, 0);
      }
    }
    __syncthreads();   // one barrier/K-step: WAR on buf b + drains buf b^1 loads
  }

  // epilogue; C/D layout: row = quad*4 + reg, col = lane&15 (m89-verified)
#pragma unroll
  for (int mi = 0; mi < 4; ++mi) {
#pragma unroll
    for (int r = 0; r < 4; ++r) {
      const int row = m0 + wm * 64 + mi * 16 + quad * 4 + r;
      if constexpr (MODE == 3) {
        unsigned short* yr = yrow(ylo, yhi, row);
#pragma unroll
        for (int ni = 0; ni < 4; ++ni) {
          const int c = n0 + wn * 64 + ni * 16 + l16;
          yr[c] = f2bf(acc[mi][ni][r] + bias[c]);
        }
      } else if constexpr (MODE == 4) {
        if (row < cnt_end) {
          const int t = slot_tok[row] >> 1;
          const float w = wts[row];            // slot_wt passed in wts param
#pragma unroll
          for (int ni = 0; ni < 4; ++ni) {
            const int c = n0 + wn * 64 + ni * 16 + l16;
            atomicAdd(&outF[(long)t * DH + c], w * (acc[mi][ni][r] + bias[c]));
          }
        }
      } else if constexpr (MODE == 2) {
        const int s0 = slot_pos[2 * row], s1 = slot_pos[2 * row + 1];
        const float w0 = wts[2 * row], w1 = wts[2 * row + 1];
        const unsigned short* y0 = yrow(ylo, yhi, s0);
        const unsigned short* y1 = yrow(ylo, yhi, s1);
#pragma unroll
        for (int ni = 0; ni < 4; ++ni) {
          const int c = n0 + wn * 64 + ni * 16 + l16;
          outF[(long)row * DH + c] =
              acc[mi][ni][r] + bias[c] + w0 * bf2f(y0[c]) + w1 * bf2f(y1[c]);
        }
      } else if constexpr (MODE == 5) {
#pragma unroll
        for (int ni = 0; ni < 4; ++ni) {
          const int c = n0 + wn * 64 + ni * 16 + l16;
          outF[(long)row * DH + c] = acc[mi][ni][r] + bias[c];
        }
      } else if constexpr (MODE == 1) {
#pragma unroll
        for (int ni = 0; ni < 4; ++ni) {
          const int c = n0 + wn * 64 + ni * 16 + l16;
          outH[(long)row * DF + c] = f2bf(gelu_fast(acc[mi][ni][r] + bias[c]));
        }
      } else {  // MODE 0: bint pairing (r2/r3-verified mapping)
        // bint row n0+wn*64+2p*16+l16 = w1 row of h-col ch; +16 = w3 row.
#pragma unroll
        for (int p = 0; p < 2; ++p) {
          const int ch = ((n0 + wn * 64) >> 1) + p * 16 + l16;
          const float h1 = acc[mi][2 * p][r] + bias1[ch];
          const float h3 = acc[mi][2 * p + 1][r] + bias2[ch];
          outH[(long)row * DF + ch] = f2bf(gelu_fast(h1) * h3);
        }
      }
    }
  }
}

// ---------------------------------------------------------------------------
extern "C" void kernel_launch(void* const* d_in, const int* in_sizes, int n_in,
                              void* d_out, int out_size, void* d_ws, size_t ws_size,
                              hipStream_t stream) {
  const float* x     = (const float*)d_in[0];
  const float* gw    = (const float*)d_in[1];
  const float* fc1w  = (const float*)d_in[2];
  const float* fc1bs = (const float*)d_in[3];
  const float* fc2w  = (const float*)d_in[4];
  const float* fc2bs = (const float*)d_in[5];
  const float* w1w   = (const float*)d_in[6];
  const float* w1bs  = (const float*)d_in[7];
  const float* w3w   = (const float*)d_in[8];
  const float* w3bs  = (const float*)d_in[9];
  const float* w2w   = (const float*)d_in[10];
  const float* w2bs  = (const float*)d_in[11];
  float* out = (float*)d_out;

  char* p = (char*)d_ws;
  auto take = [&](size_t b) { char* r = p; p += (b + 255) & ~(size_t)255; return r; };
  unsigned short* xb   = (unsigned short*)take((size_t)T_TOK * DH * 2);
  unsigned short* fc1b = (unsigned short*)take((size_t)NE * DF * DH * 2);
  unsigned short* fc2b = (unsigned short*)take((size_t)NE * DH * DF * 2);
  unsigned short* bint = (unsigned short*)take((size_t)2 * DF * DH * 2);  // w1/w3 zip
  unsigned short* w2b  = (unsigned short*)take((size_t)DH * DF * 2);
  unsigned short* h    = (unsigned short*)take((size_t)NROW_H * DF * 2);
  int*   eids     = (int*)take((size_t)NSLOT * 4);
  float* wts      = (float*)take((size_t)NSLOT * 4);
  int*   hcur     = (int*)take(NE * 64 * 4);
  int*   cur2     = (int*)take(NE * 64 * 4);
  int*   sched    = (int*)take(32 * 4);
  int*   slot_tok = (int*)take((size_t)NROW_H * 4);
  float* slot_wt  = (float*)take((size_t)NROW_H * 4);
  int*   slot_pos = (int*)take((size_t)NSLOT * 4);
  // common footprint: ~224.4e6 B (same as proven r4 layout; bint == w1b+w3b)

  // path A extra: high rows of the routed-y buffer; low rows alias fc1b,
  // which is dead after routed fc1 (stream-ordered before routed fc2 writes y)
  const size_t yhi_bytes = (size_t)(NROW_H - T_TOK) * DH * 2;
  const bool pathA = ((size_t)(p - (char*)d_ws) + yhi_bytes) <= ws_size;
  unsigned short* ylo = fc1b;
  unsigned short* yhi = pathA ? (unsigned short*)take(yhi_bytes) : nullptr;

  hipMemsetAsync(hcur, 0, NE * 64 * sizeof(int), stream);

  auto conv = [&](const float* s, unsigned short* d, long n) {
    int n4 = (int)(n >> 2);
    conv_f32_bf16<<<(n4 + 255) / 256, 256, 0, stream>>>(s, d, n4);
  };
  conv(fc1w, fc1b, (long)NE * DF * DH);
  conv(fc2w, fc2b, (long)NE * DH * DF);
  conv(w2w, w2b, (long)DH * DF);
  conv_interleave_k<<<2 * DF, 192, 0, stream>>>(w1w, w3w, bint);

  // gate: topk (no atomics) -> histogram -> scan -> scatter
  gate_topk<<<T_TOK / 4, 256, 0, stream>>>(x, gw, xb, eids, wts);
  hist_k<<<NSLOT / 256, 256, 0, stream>>>(eids, hcur);
  scan_k<<<1, 64, 0, stream>>>(hcur, sched, cur2);
  scatter_k<<<NSLOT / 256, 256, 0, stream>>>(eids, wts, cur2, slot_tok, slot_wt,
                                             slot_pos);

  if (pathA) {
    // routed fc1 -> routed fc2 (y rows) -> shared fc1 -> shared fc2+combine
    gemm_k<1, 16, 16 * MT_ROUTED><<<16 * MT_ROUTED, 256, 0, stream>>>(
        xb, fc1b, fc1bs, nullptr, nullptr, h, DH,
        sched, slot_tok, nullptr, nullptr, nullptr, nullptr);
    gemm_k<3, 6, 6 * MT_ROUTED><<<6 * MT_ROUTED, 256, 0, stream>>>(
        h, fc2b, fc2bs, nullptr, nullptr, nullptr, DF,
        sched, nullptr, nullptr, nullptr, ylo, yhi);
    gemm_k<0, 32, 32 * (T_TOK / 128)><<<32 * (T_TOK / 128), 256, 0, stream>>>(
        xb, bint, w1bs, w3bs, nullptr, h, DH,
        nullptr, nullptr, nullptr, nullptr, nullptr, nullptr);
    gemm_k<2, 6, 6 * (T_TOK / 128)><<<6 * (T_TOK / 128), 256, 0, stream>>>(
        h, w2b, w2bs, nullptr, out, nullptr, DF,
        nullptr, nullptr, slot_pos, wts, ylo, yhi);
  } else {
    // fallback (proven footprint/order): shared plain, routed atomic
    gemm_k<0, 32, 32 * (T_TOK / 128)><<<32 * (T_TOK / 128), 256, 0, stream>>>(
        xb, bint, w1bs, w3bs, nullptr, h, DH,
        nullptr, nullptr, nullptr, nullptr, nullptr, nullptr);
    gemm_k<5, 6, 6 * (T_TOK / 128)><<<6 * (T_TOK / 128), 256, 0, stream>>>(
        h, w2b, w2bs, nullptr, out, nullptr, DF,
        nullptr, nullptr, nullptr, nullptr, nullptr, nullptr);
    gemm_k<1, 16, 16 * MT_ROUTED><<<16 * MT_ROUTED, 256, 0, stream>>>(
        xb, fc1b, fc1bs, nullptr, nullptr, h, DH,
        sched, slot_tok, nullptr, nullptr, nullptr, nullptr);
    gemm_k<4, 6, 6 * MT_ROUTED><<<6 * MT_ROUTED, 256, 0, stream>>>(
        h, fc2b, fc2bs, nullptr, out, nullptr, DF,
        sched, slot_tok, nullptr, slot_wt, nullptr, nullptr);
  }
}